// Round 1
// baseline (1797.753 us; speedup 1.0000x reference)
//
#include <hip/hip_runtime.h>
#include <cfloat>
#include <cmath>

// ---------------------------------------------------------------------------
// Qwen3Attention with pervasive fake-quantization, fp32 end-to-end.
// B=2 S=1024 HID=2048 NH=16 NKV=8 D=128.
// Strategy: exploit monotonicity of fq16 so every global-quantizer range is
// either (a) reduced via GEMM-epilogue / pass atomics, or (b) derived
// analytically from already-reduced scalars. Raw logits staged in-place in
// d_out's attn region; final quantized softmax overwrites them.
// ---------------------------------------------------------------------------

#define FQ_EPS      1.5259021896696422e-09f   // 0.0001/65535
#define SCALING_F   0.08838834764831845f      // 128**-0.5
#define S_LEN       1024

// ---- float <-> order-preserving unsigned encoding (for atomic min/max) ----
__device__ __forceinline__ unsigned f2o(float f){
  unsigned u = __float_as_uint(f);
  return (u & 0x80000000u) ? ~u : (u | 0x80000000u);
}
__device__ __forceinline__ float o2f(unsigned u){
  return __uint_as_float((u & 0x80000000u) ? (u ^ 0x80000000u) : ~u);
}
// stats slots are spread by 16 words (64B) to avoid same-cacheline atomic serialization
__device__ __forceinline__ float dec_slot(const unsigned* st, int s){ return o2f(st[s*16]); }

// ---- fq16 helpers (exact fp32 replica of reference ops) ----
struct FQP { float scale, zp; };
__device__ __forceinline__ FQP fqp_raw(float mn, float mx){
  FQP p; p.scale = fmaxf((mx - mn)/65535.0f, FQ_EPS); p.zp = rintf(-mn/p.scale); return p;
}
__device__ __forceinline__ FQP fqp(float mn0, float mx0){
  return fqp_raw(fminf(mn0, 0.0f), fmaxf(mx0, 0.0f));
}
__device__ __forceinline__ float fqa(float x, FQP p){
  float q = rintf(x/p.scale) + p.zp;
  q = fminf(fmaxf(q, 0.0f), 65535.0f);
  return (q - p.zp)*p.scale;
}
__device__ __forceinline__ float fq8(float x, float s){
  return fminf(fmaxf(rintf(x/s), -128.0f), 127.0f)*s;
}

// ---- block reductions (blockDim == 256) ----
__device__ __forceinline__ float bred_min(float v, float* red){
  int tid = threadIdx.x; red[tid] = v; __syncthreads();
  for (int s = 128; s > 0; s >>= 1){ if (tid < s) red[tid] = fminf(red[tid], red[tid+s]); __syncthreads(); }
  float r = red[0]; __syncthreads(); return r;
}
__device__ __forceinline__ float bred_max(float v, float* red){
  int tid = threadIdx.x; red[tid] = v; __syncthreads();
  for (int s = 128; s > 0; s >>= 1){ if (tid < s) red[tid] = fmaxf(red[tid], red[tid+s]); __syncthreads(); }
  float r = red[0]; __syncthreads(); return r;
}
__device__ __forceinline__ float bred_sum(float v, float* red){
  int tid = threadIdx.x; red[tid] = v; __syncthreads();
  for (int s = 128; s > 0; s >>= 1){ if (tid < s) red[tid] = red[tid] + red[tid+s]; __syncthreads(); }
  float r = red[0]; __syncthreads(); return r;
}

// ---- stats slot map (even = min slot, odd = max slot) ----
// 0/1 hs | 2/3 qlin | 4/5 klin | 6/7 vlin | 8/9 qn | 10/11 qn(half2) | 12/13 kn
// 14/15 kn(half2) | 16/17 q*c | 18/19 qrh*s | 20/21 k*c | 22/23 krh*s
// 24/25 qsum | 26/27 ksum | 28/29 logits | 31 logitsUnmaskedMax
// 32 denomMin | 35 maxOfRowMins | 36/37 ctx

__global__ void k_init(unsigned* stats, unsigned* rowmin, int nrows){
  int i = blockIdx.x*blockDim.x + threadIdx.x;
  if (i < 1024) stats[i] = (((i & 15) == 0) && (((i >> 4) & 1) == 0)) ? 0xFFFFFFFFu : 0u;
  if (i < nrows) rowmin[i] = 0xFFFFFFFFu;
}

// lpbq weight quantization: per-32-contiguous-block symmetric int4
__global__ __launch_bounds__(256) void k_quantw(const float* __restrict__ W, float* __restrict__ Wq, int n){
  int i = blockIdx.x*256 + threadIdx.x;
  float v = W[i];
  float am = fabsf(v);
  #pragma unroll
  for (int m = 1; m < 32; m <<= 1) am = fmaxf(am, __shfl_xor(am, m, 64));
  float s = fmaxf(am/7.0f, 1e-12f);
  float q = fminf(fmaxf(rintf(v/s), -8.0f), 7.0f);
  Wq[i] = q*s;
}

__global__ __launch_bounds__(256) void k_minmax(const float* __restrict__ x, int n, unsigned* stats, int slot){
  float mn = FLT_MAX, mx = -FLT_MAX;
  for (int i = blockIdx.x*256 + threadIdx.x; i < n; i += gridDim.x*256){
    float v = x[i]; mn = fminf(mn, v); mx = fmaxf(mx, v);
  }
  __shared__ float red[256];
  float bmn = bred_min(mn, red), bmx = bred_max(mx, red);
  if (threadIdx.x == 0){ atomicMin(&stats[slot*16], f2o(bmn)); atomicMax(&stats[(slot+1)*16], f2o(bmx)); }
}

__global__ __launch_bounds__(256) void k_fq_ew(const float* __restrict__ x, float* __restrict__ y, int n,
                                               const unsigned* stats, int slot){
  FQP p = fqp(dec_slot(stats, slot), dec_slot(stats, slot+1));
  for (int i = blockIdx.x*256 + threadIdx.x; i < n; i += gridDim.x*256) y[i] = fqa(x[i], p);
}

// C[M,N] = A[M,K] * B[N,K]^T. Optional fq16 on A load (slotA>=0), optional
// min/max stats of C (slotC>=0). 64x64 tile, BK=16, 4x4 per thread.
__global__ __launch_bounds__(256) void k_gemm_nt(const float* __restrict__ A, const float* __restrict__ Bw,
                                                 float* __restrict__ C, int N, int K,
                                                 unsigned* stats, int slotA, int slotC){
  __shared__ float As[16][68], Bs[16][68];
  __shared__ float red[256];
  FQP pA; if (slotA >= 0) pA = fqp(dec_slot(stats, slotA), dec_slot(stats, slotA+1));
  int tid = threadIdx.x, tx = tid & 15, ty = tid >> 4;
  int bm = blockIdx.y*64, bn = blockIdx.x*64;
  int lm = tid >> 2, lk = (tid & 3) << 2;
  const float* Ap = A + (size_t)(bm + lm)*K + lk;
  const float* Bp = Bw + (size_t)(bn + lm)*K + lk;
  float acc[4][4] = {};
  for (int k0 = 0; k0 < K; k0 += 16){
    float4 av = *(const float4*)(Ap + k0);
    float4 bv = *(const float4*)(Bp + k0);
    if (slotA >= 0){ av.x = fqa(av.x, pA); av.y = fqa(av.y, pA); av.z = fqa(av.z, pA); av.w = fqa(av.w, pA); }
    As[lk+0][lm] = av.x; As[lk+1][lm] = av.y; As[lk+2][lm] = av.z; As[lk+3][lm] = av.w;
    Bs[lk+0][lm] = bv.x; Bs[lk+1][lm] = bv.y; Bs[lk+2][lm] = bv.z; Bs[lk+3][lm] = bv.w;
    __syncthreads();
    #pragma unroll
    for (int kk = 0; kk < 16; kk++){
      const float4 a4 = *(const float4*)(&As[kk][ty << 2]);
      const float4 b4 = *(const float4*)(&Bs[kk][tx << 2]);
      float a[4] = {a4.x, a4.y, a4.z, a4.w};
      float b[4] = {b4.x, b4.y, b4.z, b4.w};
      #pragma unroll
      for (int i = 0; i < 4; i++)
        #pragma unroll
        for (int j = 0; j < 4; j++) acc[i][j] += a[i]*b[j];
    }
    __syncthreads();
  }
  float mn = FLT_MAX, mx = -FLT_MAX;
  #pragma unroll
  for (int i = 0; i < 4; i++)
    #pragma unroll
    for (int j = 0; j < 4; j++){
      float v = acc[i][j];
      C[(size_t)(bm + (ty<<2) + i)*N + bn + (tx<<2) + j] = v;
      mn = fminf(mn, v); mx = fmaxf(mx, v);
    }
  if (slotC >= 0){
    float bmn = bred_min(mn, red), bmx = bred_max(mx, red);
    if (tid == 0){ atomicMin(&stats[slotC*16], f2o(bmn)); atomicMax(&stats[(slotC+1)*16], f2o(bmx)); }
  }
}

// fq16(A) then per-128 rmsnorm; writes (B,NH,S,D); reduces full + second-half ranges
__global__ __launch_bounds__(256) void k_rms(const float* __restrict__ lin, float* __restrict__ buf,
                                             const float* __restrict__ gw, unsigned* stats,
                                             int slot_lin, int slot_out, int NHh, int rows){
  FQP pA = fqp(dec_slot(stats, slot_lin), dec_slot(stats, slot_lin+1));
  int lane = threadIdx.x & 63;
  int wv = (blockIdx.x*256 + threadIdx.x) >> 6;
  int nwv = (gridDim.x*256) >> 6;
  float w0 = gw[lane], w1 = gw[lane + 64];
  float fmn = FLT_MAX, fmx = -FLT_MAX, hmn = FLT_MAX, hmx = -FLT_MAX;
  for (int r = wv; r < rows; r += nwv){
    int h = r % NHh; int rem = r / NHh; int s2 = rem & 1023; int b = rem >> 10;
    const float* src = lin + (size_t)r*128;
    float x0 = fqa(src[lane], pA), x1 = fqa(src[lane + 64], pA);
    float ss = x0*x0 + x1*x1;
    #pragma unroll
    for (int m = 1; m < 64; m <<= 1) ss += __shfl_xor(ss, m, 64);
    float rr = 1.0f/sqrtf(ss*(1.0f/128.0f) + 1e-6f);
    float y0 = x0*rr*w0, y1 = x1*rr*w1;
    float* dst = buf + ((size_t)((b*NHh + h) << 10) + s2)*128;
    dst[lane] = y0; dst[lane + 64] = y1;
    fmn = fminf(fmn, fminf(y0, y1)); fmx = fmaxf(fmx, fmaxf(y0, y1));
    hmn = fminf(hmn, y1); hmx = fmaxf(hmx, y1);
  }
  __shared__ float red[256];
  float a = bred_min(fmn, red), bb = bred_max(fmx, red);
  float c = bred_min(hmn, red), d = bred_max(hmx, red);
  if (threadIdx.x == 0){
    atomicMin(&stats[slot_out*16], f2o(a));     atomicMax(&stats[(slot_out+1)*16], f2o(bb));
    atomicMin(&stats[(slot_out+2)*16], f2o(c)); atomicMax(&stats[(slot_out+3)*16], f2o(d));
  }
}

// derive fqB (rmsnorm-out), fqC (=fq16 again), fqE (neg half), fqF (rot concat) from reduced scalars
struct RopeQ { FQP B, C, E, F; };
__device__ RopeQ derive_rope(const unsigned* st, int base){
  float ymn = dec_slot(st, base),   ymx = dec_slot(st, base+1);
  float y2mn = dec_slot(st, base+2), y2mx = dec_slot(st, base+3);
  RopeQ r;
  r.B = fqp(ymn, ymx);
  float zmn = fqa(ymn, r.B), zmx = fqa(ymx, r.B);
  r.C = fqp(zmn, zmx);
  float zlo = fqa(zmn, r.C), zhi = fqa(zmx, r.C);
  float z2lo = fqa(fqa(y2mn, r.B), r.C), z2hi = fqa(fqa(y2mx, r.B), r.C);
  r.E = fqp(-z2hi, -z2lo);
  float nlo = fqa(-z2hi, r.E), nhi = fqa(-z2lo, r.E);
  r.F = fqp_raw(fminf(fminf(zlo, nlo), 0.0f), fmaxf(fmaxf(zhi, nhi), 0.0f));
  return r;
}

// RoPE. do_write=0: reduce ranges of q*cos and rot(q)*sin.  do_write=1: write
// fqD(q*c)+fqG(rh*s) in place and reduce its range (pre-fqH input).
__global__ __launch_bounds__(256) void k_rope(float* __restrict__ buf, const float* __restrict__ cosp,
                                              const float* __restrict__ sinp, unsigned* stats,
                                              int slot_norm, int slot_prod, int slot_sum,
                                              int NHh, int rows, int do_write){
  RopeQ R = derive_rope(stats, slot_norm);
  FQP pD, pG;
  if (do_write){
    pD = fqp(dec_slot(stats, slot_prod),   dec_slot(stats, slot_prod+1));
    pG = fqp(dec_slot(stats, slot_prod+2), dec_slot(stats, slot_prod+3));
  }
  int lane = threadIdx.x & 63;
  int wv = (blockIdx.x*256 + threadIdx.x) >> 6, nwv = (gridDim.x*256) >> 6;
  float m0 = FLT_MAX, M0 = -FLT_MAX, m1 = FLT_MAX, M1 = -FLT_MAX;
  for (int r = wv; r < rows; r += nwv){
    int s2 = r & 1023; int bh = r >> 10; int b = bh/NHh;
    float* base = buf + (size_t)r*128;
    float y0 = base[lane], y1 = base[lane + 64];
    float z0 = fqa(fqa(y0, R.B), R.C), z1 = fqa(fqa(y1, R.B), R.C);
    const float* cr = cosp + (size_t)((b << 10) + s2)*128;
    const float* sr = sinp + (size_t)((b << 10) + s2)*128;
    float c0 = cr[lane], c1 = cr[lane + 64], sn0 = sr[lane], sn1 = sr[lane + 64];
    float pc0 = z0*c0, pc1 = z1*c1;
    float rh0 = fqa(fqa(-z1, R.E), R.F);   // d<64: fqF(fqE(-x2))
    float rh1 = fqa(z0, R.F);              // d>=64: fqF(x1)
    float ps0 = rh0*sn0, ps1 = rh1*sn1;
    if (!do_write){
      m0 = fminf(m0, fminf(pc0, pc1)); M0 = fmaxf(M0, fmaxf(pc0, pc1));
      m1 = fminf(m1, fminf(ps0, ps1)); M1 = fmaxf(M1, fmaxf(ps0, ps1));
    } else {
      float sv0 = fqa(pc0, pD) + fqa(ps0, pG);
      float sv1 = fqa(pc1, pD) + fqa(ps1, pG);
      base[lane] = sv0; base[lane + 64] = sv1;
      m0 = fminf(m0, fminf(sv0, sv1)); M0 = fmaxf(M0, fmaxf(sv0, sv1));
    }
  }
  __shared__ float red[256];
  if (!do_write){
    float a = bred_min(m0, red), bb = bred_max(M0, red);
    float c = bred_min(m1, red), d = bred_max(M1, red);
    if (threadIdx.x == 0){
      atomicMin(&stats[slot_prod*16], f2o(a));     atomicMax(&stats[(slot_prod+1)*16], f2o(bb));
      atomicMin(&stats[(slot_prod+2)*16], f2o(c)); atomicMax(&stats[(slot_prod+3)*16], f2o(d));
    }
  } else {
    float a = bred_min(m0, red), bb = bred_max(M0, red);
    if (threadIdx.x == 0){ atomicMin(&stats[slot_sum*16], f2o(a)); atomicMax(&stats[(slot_sum+1)*16], f2o(bb)); }
  }
}

// QK^T: fqH(q) . fq8(fqH(k)) per (b,h); writes raw logits; reduces global
// min/max, unmasked max, per-row min.
__global__ __launch_bounds__(256) void k_gemm_qk(const float* __restrict__ qbuf, const float* __restrict__ kbuf,
                                                 float* __restrict__ logits, unsigned* stats,
                                                 unsigned* rowmin){
  int z = blockIdx.z, b = z >> 4, h = z & 15;
  FQP pQ = fqp(dec_slot(stats, 24), dec_slot(stats, 25));
  FQP pK = fqp(dec_slot(stats, 26), dec_slot(stats, 27));
  float klo = fqa(dec_slot(stats, 26), pK), khi = fqa(dec_slot(stats, 27), pK);
  float k8s = fmaxf(fmaxf(fabsf(klo), fabsf(khi))/127.0f, 1e-12f);
  __shared__ float As[16][68], Bs[16][68];
  __shared__ float rowred[64][17];
  __shared__ float red[256];
  int tid = threadIdx.x, tx = tid & 15, ty = tid >> 4;
  int bm = blockIdx.y*64, bn = blockIdx.x*64;
  int lm = tid >> 2, lk = (tid & 3) << 2;
  const float* Ap = qbuf + (size_t)z*S_LEN*128 + (size_t)(bm + lm)*128 + lk;
  const float* Bp = kbuf + (size_t)(b*8 + (h >> 1))*S_LEN*128 + (size_t)(bn + lm)*128 + lk;
  float acc[4][4] = {};
  for (int k0 = 0; k0 < 128; k0 += 16){
    float4 av = *(const float4*)(Ap + k0);
    float4 bv = *(const float4*)(Bp + k0);
    As[lk+0][lm] = fqa(av.x, pQ); As[lk+1][lm] = fqa(av.y, pQ);
    As[lk+2][lm] = fqa(av.z, pQ); As[lk+3][lm] = fqa(av.w, pQ);
    Bs[lk+0][lm] = fq8(fqa(bv.x, pK), k8s); Bs[lk+1][lm] = fq8(fqa(bv.y, pK), k8s);
    Bs[lk+2][lm] = fq8(fqa(bv.z, pK), k8s); Bs[lk+3][lm] = fq8(fqa(bv.w, pK), k8s);
    __syncthreads();
    #pragma unroll
    for (int kk = 0; kk < 16; kk++){
      const float4 a4 = *(const float4*)(&As[kk][ty << 2]);
      const float4 b4 = *(const float4*)(&Bs[kk][tx << 2]);
      float a[4] = {a4.x, a4.y, a4.z, a4.w};
      float b2[4] = {b4.x, b4.y, b4.z, b4.w};
      #pragma unroll
      for (int i = 0; i < 4; i++)
        #pragma unroll
        for (int j = 0; j < 4; j++) acc[i][j] += a[i]*b2[j];
    }
    __syncthreads();
  }
  float* Cp = logits + (size_t)z*S_LEN*S_LEN;
  float mn = FLT_MAX, mx = -FLT_MAX, mxU = -FLT_MAX;
  float rmin[4] = {FLT_MAX, FLT_MAX, FLT_MAX, FLT_MAX};
  #pragma unroll
  for (int i = 0; i < 4; i++)
    #pragma unroll
    for (int j = 0; j < 4; j++){
      int row = bm + (ty << 2) + i, col = bn + (tx << 2) + j;
      float v = acc[i][j];
      Cp[(size_t)row*S_LEN + col] = v;
      mn = fminf(mn, v); mx = fmaxf(mx, v);
      if (col <= row) mxU = fmaxf(mxU, v);
      rmin[i] = fminf(rmin[i], v);
    }
  #pragma unroll
  for (int i = 0; i < 4; i++) rowred[(ty << 2) + i][tx] = rmin[i];
  __syncthreads();
  if (tid < 64){
    float m = rowred[tid][0];
    #pragma unroll
    for (int c = 1; c < 16; c++) m = fminf(m, rowred[tid][c]);
    atomicMin(&rowmin[(z << 10) + bm + tid], f2o(m));
  }
  float bmn = bred_min(mn, red), bmx = bred_max(mx, red), bmU = bred_max(mxU, red);
  if (tid == 0){
    atomicMin(&stats[28*16], f2o(bmn));
    atomicMax(&stats[29*16], f2o(bmx));
    atomicMax(&stats[31*16], f2o(bmU));
  }
}

__global__ __launch_bounds__(256) void k_rowstat_m2(const unsigned* __restrict__ rowmin, unsigned* stats, int n){
  float lm = -FLT_MAX;
  for (int i = threadIdx.x; i < n; i += 256) lm = fmaxf(lm, o2f(rowmin[i]));
  __shared__ float red[256];
  float m = bred_max(lm, red);
  if (threadIdx.x == 0) stats[35*16] = f2o(m);
}
__global__ __launch_bounds__(256) void k_denom_min(const float* __restrict__ denomS, unsigned* stats, int n){
  float lm = FLT_MAX;
  for (int i = threadIdx.x; i < n; i += 256) lm = fminf(lm, denomS[i]);
  __shared__ float red[256];
  float m = bred_min(lm, red);
  if (threadIdx.x == 0) stats[32*16] = f2o(m);
}

// derived quantizer chain for the logits pipeline (all from 4 reduced scalars)
struct LogitQ { FQP f1, f2, fam, fvv, f3; float sc, c20; };
__device__ LogitQ derive_logit(const unsigned* st){
  LogitQ L;
  FQP ps = fqp(SCALING_F, SCALING_F); L.sc = fqa(SCALING_F, ps);
  FQP p20 = fqp(-20.0f, -20.0f);      L.c20 = fqa(-20.0f, p20);
  float gmn = dec_slot(st, 28), gmx = dec_slot(st, 29);
  float gU = dec_slot(st, 31), M2 = dec_slot(st, 35);
  L.f1 = fqp(gmn, gmx);
  float l1lo = fqa(gmn, L.f1), l1hi = fqa(gmx, L.f1);
  L.f2 = fqp(l1lo*L.sc, l1hi*L.sc);
  float amlo = fqa(fqa(gmn, L.f1)*L.sc, L.f2);
  float amhi = fqa(fqa(M2, L.f1)*L.sc, L.f2);
  L.fam = fqp(amlo, amhi);
  float vslo = fqa(amlo, L.fam) + L.c20, vshi = fqa(amhi, L.fam) + L.c20;
  L.fvv = fqp(vslo, vshi);
  float mn3 = fqa(vslo, L.fvv);
  float mx3 = fqa(fqa(gU, L.f1)*L.sc, L.f2);
  L.f3 = fqp(mn3, mx3);
  return L;
}
__device__ __forceinline__ float masked_a3(float raw, int t, int s, const LogitQ& L, float vv3){
  float a2 = fqa(fqa(raw, L.f1)*L.sc, L.f2);
  return (t <= s) ? fqa(a2, L.f3) : vv3;
}
__device__ __forceinline__ float row_vv3(const unsigned* rowmin, int row, const LogitQ& L){
  float tr = fqa(fqa(o2f(rowmin[row]), L.f1)*L.sc, L.f2);
  return fqa(fqa(fqa(tr, L.fam) + L.c20, L.fvv), L.f3);
}

// pass B: per-row max + softmax denominator (raw logits -> mS, denomS)
__global__ __launch_bounds__(256) void k_softmax_stats(const float* __restrict__ logits,
                                                       const unsigned* __restrict__ rowmin,
                                                       float* __restrict__ mS, float* __restrict__ denomS,
                                                       const unsigned* stats){
  LogitQ L = derive_logit(stats);
  int row = blockIdx.x; int s = row & 1023;
  float vv3 = row_vv3(rowmin, row, L);
  const float* rp = logits + (size_t)row*S_LEN;
  int tid = threadIdx.x;
  float vals[4]; float lm = -FLT_MAX;
  #pragma unroll
  for (int i = 0; i < 4; i++){
    int t = (i << 8) + tid;
    vals[i] = masked_a3(rp[t], t, s, L, vv3);
    lm = fmaxf(lm, vals[i]);
  }
  __shared__ float red[256];
  float m = bred_max(lm, red);
  float ls = 0.0f;
  #pragma unroll
  for (int i = 0; i < 4; i++) ls += expf(vals[i] - m);
  float dn = bred_sum(ls, red);
  if (tid == 0){ mS[row] = m; denomS[row] = dn; }
}

// pass C: recompute a3, softmax, fq16-quantize, overwrite in place (final attn output)
__global__ __launch_bounds__(256) void k_softmax_write(float* __restrict__ logits,
                                                       const unsigned* __restrict__ rowmin,
                                                       const float* __restrict__ mS,
                                                       const float* __restrict__ denomS,
                                                       const unsigned* stats){
  LogitQ L = derive_logit(stats);
  float maxp = 1.0f/dec_slot(stats, 32);
  FQP p4 = fqp(0.0f, maxp);
  int row = blockIdx.x; int s = row & 1023;
  float vv3 = row_vv3(rowmin, row, L);
  float m = mS[row], dn = denomS[row];
  float* rp = logits + (size_t)row*S_LEN;
  int tid = threadIdx.x;
  #pragma unroll
  for (int i = 0; i < 4; i++){
    int t = (i << 8) + tid;
    float a3 = masked_a3(rp[t], t, s, L, vv3);
    float p = expf(a3 - m)/dn;
    rp[t] = fqa(p, p4);   // each element owned by exactly one thread -> in-place safe
  }
}

// PV: attn(quantized) @ fq8(fq16(v)); writes ctx in (B,S,NH*D); reduces ctx range
__global__ __launch_bounds__(256) void k_gemm_pv(const float* __restrict__ attn, const float* __restrict__ vlin,
                                                 float* __restrict__ ctx, unsigned* stats){
  int z = blockIdx.z, b = z >> 4, h = z & 15, kv = h >> 1;
  FQP pv = fqp(dec_slot(stats, 6), dec_slot(stats, 7));
  float vlo = fqa(dec_slot(stats, 6), pv), vhi = fqa(dec_slot(stats, 7), pv);
  float v8s = fmaxf(fmaxf(fabsf(vlo), fabsf(vhi))/127.0f, 1e-12f);
  __shared__ float As[16][68], Bs[16][68];
  __shared__ float red[256];
  int tid = threadIdx.x, tx = tid & 15, ty = tid >> 4;
  int bm = blockIdx.y*64, bn = blockIdx.x*64;
  int lm = tid >> 2, lk = (tid & 3) << 2;      // A staging
  int ln = (tid & 15) << 2, lk2 = tid >> 4;    // B staging
  const float* Ap = attn + (size_t)z*S_LEN*S_LEN + (size_t)(bm + lm)*S_LEN + lk;
  const float* Bbase = vlin + (size_t)(b*S_LEN)*1024 + (size_t)kv*128 + bn;
  float acc[4][4] = {};
  for (int k0 = 0; k0 < S_LEN; k0 += 16){
    float4 av = *(const float4*)(Ap + k0);
    As[lk+0][lm] = av.x; As[lk+1][lm] = av.y; As[lk+2][lm] = av.z; As[lk+3][lm] = av.w;
    float4 bv = *(const float4*)(Bbase + (size_t)(k0 + lk2)*1024 + ln);
    float4 tb;
    tb.x = fq8(fqa(bv.x, pv), v8s); tb.y = fq8(fqa(bv.y, pv), v8s);
    tb.z = fq8(fqa(bv.z, pv), v8s); tb.w = fq8(fqa(bv.w, pv), v8s);
    *(float4*)(&Bs[lk2][ln]) = tb;
    __syncthreads();
    #pragma unroll
    for (int kk = 0; kk < 16; kk++){
      const float4 a4 = *(const float4*)(&As[kk][ty << 2]);
      const float4 b4 = *(const float4*)(&Bs[kk][tx << 2]);
      float a[4] = {a4.x, a4.y, a4.z, a4.w};
      float b2[4] = {b4.x, b4.y, b4.z, b4.w};
      #pragma unroll
      for (int i = 0; i < 4; i++)
        #pragma unroll
        for (int j = 0; j < 4; j++) acc[i][j] += a[i]*b2[j];
    }
    __syncthreads();
  }
  float mn = FLT_MAX, mx = -FLT_MAX;
  #pragma unroll
  for (int i = 0; i < 4; i++)
    #pragma unroll
    for (int j = 0; j < 4; j++){
      float v = acc[i][j];
      ctx[((size_t)(b << 10) + bm + (ty << 2) + i)*2048 + h*128 + bn + (tx << 2) + j] = v;
      mn = fminf(mn, v); mx = fmaxf(mx, v);
    }
  float bmn = bred_min(mn, red), bmx = bred_max(mx, red);
  if (tid == 0){ atomicMin(&stats[36*16], f2o(bmn)); atomicMax(&stats[37*16], f2o(bmx)); }
}

extern "C" void kernel_launch(void* const* d_in, const int* in_sizes, int n_in,
                              void* d_out, int out_size, void* d_ws, size_t ws_size,
                              hipStream_t stream){
  (void)in_sizes; (void)n_in; (void)out_size; (void)ws_size;
  const float* hs   = (const float*)d_in[0];
  const float* cosp = (const float*)d_in[1];
  const float* sinp = (const float*)d_in[2];
  // d_in[3]: attention_mask (int32) — causal triu(.,1), applied analytically (t<=s unmasked)
  const float* Wq   = (const float*)d_in[4];
  const float* Wk   = (const float*)d_in[5];
  const float* Wv   = (const float*)d_in[6];
  const float* Wo   = (const float*)d_in[7];
  const float* qnw  = (const float*)d_in[8];
  const float* knw  = (const float*)d_in[9];

  float* outp = (float*)d_out;
  float* attn = outp + 4194304;          // raw-logit scratch, then final attn output

  const size_t MEG = 1u << 20;
  float* wsf  = (float*)d_ws;
  float* woq  = wsf;                     // 4M
  float* qbuf = wsf + 4*MEG;             // 4M  (B,NH,S,D)
  float* kbuf = wsf + 8*MEG;             // 2M  (B,NKV,S,D)
  float* vlin = wsf + 10*MEG;            // 2M  (B,S,NKV*D)
  float* wqq  = wsf + 12*MEG;            // 4M
  float* wkq  = wsf + 16*MEG;            // 2M
  float* wvq  = wsf + 18*MEG;            // 2M
  float* hsq  = wsf + 20*MEG;            // 4M
  float* qlin = wsf + 24*MEG;            // 4M  (reused as ctx after rms_q)
  float* ctx  = qlin;
  float* klin = wsf + 28*MEG;            // 2M
  unsigned* rowmin = (unsigned*)(wsf + 30*MEG);        // 32768
  float* mS     = wsf + 30*MEG + 32768;                // 32768
  float* denomS = wsf + 30*MEG + 65536;                // 32768
  unsigned* stats = (unsigned*)(wsf + 30*MEG + 98304); // 1024 words
  // total ws use: ~126.2 MB

  k_init<<<128, 256, 0, stream>>>(stats, rowmin, 32768);

  k_quantw<<<4194304/256, 256, 0, stream>>>(Wq, wqq, 4194304);
  k_quantw<<<2097152/256, 256, 0, stream>>>(Wk, wkq, 2097152);
  k_quantw<<<2097152/256, 256, 0, stream>>>(Wv, wvq, 2097152);
  k_quantw<<<4194304/256, 256, 0, stream>>>(Wo, woq, 4194304);

  k_minmax<<<1024, 256, 0, stream>>>(hs, 4194304, stats, 0);
  k_fq_ew<<<4096, 256, 0, stream>>>(hs, hsq, 4194304, stats, 0);

  // projections (x @ W^T), stats of raw outputs
  k_gemm_nt<<<dim3(32, 32), 256, 0, stream>>>(hsq, wqq, qlin, 2048, 2048, stats, -1, 2);
  k_gemm_nt<<<dim3(16, 32), 256, 0, stream>>>(hsq, wkq, klin, 1024, 2048, stats, -1, 4);
  k_gemm_nt<<<dim3(16, 32), 256, 0, stream>>>(hsq, wvq, vlin, 1024, 2048, stats, -1, 6);

  // fq16 + rmsnorm + fq-range reductions (full + second half for rotate_half)
  k_rms<<<1024, 256, 0, stream>>>(qlin, qbuf, qnw, stats, 2, 8, 16, 32768);
  k_rms<<<512, 256, 0, stream>>>(klin, kbuf, knw, stats, 4, 12, 8, 16384);

  // RoPE: reduce product ranges, then write fqD(q*c)+fqG(rh*s) in place
  k_rope<<<1024, 256, 0, stream>>>(qbuf, cosp, sinp, stats, 8, 16, 24, 16, 32768, 0);
  k_rope<<<512, 256, 0, stream>>>(kbuf, cosp, sinp, stats, 12, 20, 26, 8, 16384, 0);
  k_rope<<<1024, 256, 0, stream>>>(qbuf, cosp, sinp, stats, 8, 16, 24, 16, 32768, 1);
  k_rope<<<512, 256, 0, stream>>>(kbuf, cosp, sinp, stats, 12, 20, 26, 8, 16384, 1);

  // QK^T raw logits into d_out attn region + logit stats
  k_gemm_qk<<<dim3(16, 16, 32), 256, 0, stream>>>(qbuf, kbuf, attn, stats, rowmin);
  k_rowstat_m2<<<1, 256, 0, stream>>>(rowmin, stats, 32768);

  // softmax denominators, then quantized softmax written in place
  k_softmax_stats<<<32768, 256, 0, stream>>>(attn, rowmin, mS, denomS, stats);
  k_denom_min<<<1, 256, 0, stream>>>(denomS, stats, 32768);
  k_softmax_write<<<32768, 256, 0, stream>>>(attn, rowmin, mS, denomS, stats);

  // PV into ctx (B,S,NH*D) + ctx stats; then output projection with fq16(ctx) on load
  k_gemm_pv<<<dim3(2, 16, 32), 256, 0, stream>>>(attn, vlin, ctx, stats);
  k_gemm_nt<<<dim3(32, 32), 256, 0, stream>>>(ctx, woq, outp, 2048, 2048, stats, 36, -1);
}

// Round 2
// 825.746 us; speedup vs baseline: 2.1771x; 2.1771x over previous
//
#include <hip/hip_runtime.h>
#include <cfloat>
#include <cmath>

// ---------------------------------------------------------------------------
// Qwen3Attention fake-quant forward. B=2 S=1024 HID=2048 NH=16 NKV=8 D=128.
// Round 2: all GEMMs on f16 MFMA (16x16x32, fp32 accum), 128x128 tiles.
// Quantizer ranges reduced via epilogue atomics / derived analytically
// (monotonicity of fq16) exactly as in the verified round-1 pipeline.
// ---------------------------------------------------------------------------

#define FQ_EPS      1.5259021896696422e-09f   // 0.0001/65535
#define SCALING_F   0.08838834764831845f      // 128**-0.5
#define S_LEN       1024

typedef _Float16 h8_t __attribute__((ext_vector_type(8)));
typedef _Float16 h4_t __attribute__((ext_vector_type(4)));
typedef float    f4_t __attribute__((ext_vector_type(4)));

// ---- float <-> order-preserving unsigned encoding (for atomic min/max) ----
__device__ __forceinline__ unsigned f2o(float f){
  unsigned u = __float_as_uint(f);
  return (u & 0x80000000u) ? ~u : (u | 0x80000000u);
}
__device__ __forceinline__ float o2f(unsigned u){
  return __uint_as_float((u & 0x80000000u) ? (u ^ 0x80000000u) : ~u);
}
__device__ __forceinline__ float dec_slot(const unsigned* st, int s){ return o2f(st[s*16]); }

// ---- fq16 helpers ----
struct FQP { float scale, zp, inv; };
__device__ __forceinline__ FQP fqp_raw(float mn, float mx){
  FQP p; p.scale = fmaxf((mx - mn)/65535.0f, FQ_EPS); p.zp = rintf(-mn/p.scale);
  p.inv = 1.0f/p.scale; return p;
}
__device__ __forceinline__ FQP fqp(float mn0, float mx0){
  return fqp_raw(fminf(mn0, 0.0f), fmaxf(mx0, 0.0f));
}
__device__ __forceinline__ float fqa(float x, FQP p){
  float q = rintf(x*p.inv) + p.zp;
  q = fminf(fmaxf(q, 0.0f), 65535.0f);
  return (q - p.zp)*p.scale;
}
__device__ __forceinline__ float fq8(float x, float s, float si){
  return fminf(fmaxf(rintf(x*si), -128.0f), 127.0f)*s;
}

// ---- block reductions (blockDim == 256) ----
__device__ __forceinline__ float bred_min(float v, float* red){
  int tid = threadIdx.x; red[tid] = v; __syncthreads();
  for (int s = 128; s > 0; s >>= 1){ if (tid < s) red[tid] = fminf(red[tid], red[tid+s]); __syncthreads(); }
  float r = red[0]; __syncthreads(); return r;
}
__device__ __forceinline__ float bred_max(float v, float* red){
  int tid = threadIdx.x; red[tid] = v; __syncthreads();
  for (int s = 128; s > 0; s >>= 1){ if (tid < s) red[tid] = fmaxf(red[tid], red[tid+s]); __syncthreads(); }
  float r = red[0]; __syncthreads(); return r;
}
__device__ __forceinline__ float bred_sum(float v, float* red){
  int tid = threadIdx.x; red[tid] = v; __syncthreads();
  for (int s = 128; s > 0; s >>= 1){ if (tid < s) red[tid] = red[tid] + red[tid+s]; __syncthreads(); }
  float r = red[0]; __syncthreads(); return r;
}

// ---- stats slot map (even=min, odd=max) ----
// 0/1 hs | 2/3 qlin | 4/5 klin | 6/7 vlin | 8/9 qn | 10/11 qn2 | 12/13 kn | 14/15 kn2
// 16/17 q*c | 18/19 qrh*s | 20/21 k*c | 22/23 krh*s | 24/25 qsum | 26/27 ksum
// 28/29 logits | 31 unmaskedMax | 32 denomMin | 35 maxOfRowMins | 36/37 ctx

__global__ void k_init(unsigned* stats, unsigned* rowmin, int nrows){
  int i = blockIdx.x*blockDim.x + threadIdx.x;
  if (i < 1024) stats[i] = (((i & 15) == 0) && (((i >> 4) & 1) == 0)) ? 0xFFFFFFFFu : 0u;
  if (i < nrows) rowmin[i] = 0xFFFFFFFFu;
}

// lpbq weight quantization -> f16. 4 elems/thread; 8-lane shfl = 32-elem block.
__global__ __launch_bounds__(256) void k_quantw(const float* __restrict__ W, _Float16* __restrict__ Wh){
  int i = blockIdx.x*256 + threadIdx.x;
  float4 v = ((const float4*)W)[i];
  float am = fmaxf(fmaxf(fabsf(v.x), fabsf(v.y)), fmaxf(fabsf(v.z), fabsf(v.w)));
  #pragma unroll
  for (int m = 1; m < 8; m <<= 1) am = fmaxf(am, __shfl_xor(am, m, 64));
  float s = fmaxf(am/7.0f, 1e-12f), si = 1.0f/s;
  h4_t o;
  o[0] = (_Float16)(fminf(fmaxf(rintf(v.x*si), -8.0f), 7.0f)*s);
  o[1] = (_Float16)(fminf(fmaxf(rintf(v.y*si), -8.0f), 7.0f)*s);
  o[2] = (_Float16)(fminf(fmaxf(rintf(v.z*si), -8.0f), 7.0f)*s);
  o[3] = (_Float16)(fminf(fmaxf(rintf(v.w*si), -8.0f), 7.0f)*s);
  *(h4_t*)(Wh + ((size_t)i << 2)) = o;
}

__global__ __launch_bounds__(256) void k_minmax(const float* __restrict__ x, int n, unsigned* stats, int slot){
  float mn = FLT_MAX, mx = -FLT_MAX;
  for (int i = blockIdx.x*256 + threadIdx.x; i < n; i += gridDim.x*256){
    float v = x[i]; mn = fminf(mn, v); mx = fmaxf(mx, v);
  }
  __shared__ float red[256];
  float bmn = bred_min(mn, red), bmx = bred_max(mx, red);
  if (threadIdx.x == 0){ atomicMin(&stats[slot*16], f2o(bmn)); atomicMax(&stats[(slot+1)*16], f2o(bmx)); }
}

// fq16 elementwise -> f16, 4 elems/thread (n4 = n/4 groups, grid covers exactly)
__global__ __launch_bounds__(256) void k_fq_ew16(const float* __restrict__ x, _Float16* __restrict__ y,
                                                 const unsigned* stats, int slot){
  FQP p = fqp(dec_slot(stats, slot), dec_slot(stats, slot+1));
  int i = blockIdx.x*256 + threadIdx.x;
  float4 v = ((const float4*)x)[i];
  h4_t o;
  o[0] = (_Float16)fqa(v.x, p); o[1] = (_Float16)fqa(v.y, p);
  o[2] = (_Float16)fqa(v.z, p); o[3] = (_Float16)fqa(v.w, p);
  *(h4_t*)(y + ((size_t)i << 2)) = o;
}

// fq8(fq16(x)) elementwise -> f16 (for K)
__global__ __launch_bounds__(256) void k_fq8_ew16(const float* __restrict__ x, _Float16* __restrict__ y,
                                                  const unsigned* stats, int slot){
  FQP p = fqp(dec_slot(stats, slot), dec_slot(stats, slot+1));
  float lo = fqa(dec_slot(stats, slot), p), hi = fqa(dec_slot(stats, slot+1), p);
  float s8 = fmaxf(fmaxf(fabsf(lo), fabsf(hi))/127.0f, 1e-12f), s8i = 1.0f/s8;
  int i = blockIdx.x*256 + threadIdx.x;
  float4 v = ((const float4*)x)[i];
  h4_t o;
  o[0] = (_Float16)fq8(fqa(v.x, p), s8, s8i); o[1] = (_Float16)fq8(fqa(v.y, p), s8, s8i);
  o[2] = (_Float16)fq8(fqa(v.z, p), s8, s8i); o[3] = (_Float16)fq8(fqa(v.w, p), s8, s8i);
  *(h4_t*)(y + ((size_t)i << 2)) = o;
}

// ======================= f16 MFMA GEMM core (NT) ===========================
// C[M,N] = A[M,K] * B[N,K]^T, 128x128 tile, BK=32, 4 waves (2x2), each wave
// 64x64 = 4x4 fragments of 16x16x32. A/B staged in LDS as [row][32k] f16.
// AMODE 0: src f16 (ld in f16 elems). AMODE 3: src fp32, x*1024 -> f16 (PV).
template<int MODE>
__device__ __forceinline__ void stage_tile(const void* __restrict__ src, int ld, int k0,
                                           _Float16* __restrict__ dst){
  #pragma unroll
  for (int it = 0; it < 2; it++){
    int c = threadIdx.x + (it << 8);
    int row = c >> 2, off = (c & 3) << 3;
    if (MODE == 0){
      const _Float16* sp = (const _Float16*)src + (size_t)row*ld + k0 + off;
      *(h8_t*)(dst + (c << 3)) = *(const h8_t*)sp;
    } else {
      const float* sp = (const float*)src + (size_t)row*ld + k0 + off;
      float4 u = *(const float4*)sp;
      float4 w = *(const float4*)(sp + 4);
      h8_t o;
      o[0] = (_Float16)(u.x*1024.0f); o[1] = (_Float16)(u.y*1024.0f);
      o[2] = (_Float16)(u.z*1024.0f); o[3] = (_Float16)(u.w*1024.0f);
      o[4] = (_Float16)(w.x*1024.0f); o[5] = (_Float16)(w.y*1024.0f);
      o[6] = (_Float16)(w.z*1024.0f); o[7] = (_Float16)(w.w*1024.0f);
      *(h8_t*)(dst + (c << 3)) = o;
    }
  }
}

template<int AM, int BM>
__device__ __forceinline__ void hgemm_main(const void* __restrict__ A, int lda,
                                           const void* __restrict__ B, int ldb, int K,
                                           f4_t acc[4][4], _Float16* As, _Float16* Bs){
  int lane = threadIdx.x & 63, wave = threadIdx.x >> 6;
  int wm = wave & 1, wn = wave >> 1, quad = lane >> 4, l15 = lane & 15;
  for (int k0 = 0; k0 < K; k0 += 32){
    __syncthreads();
    stage_tile<AM>(A, lda, k0, As);
    stage_tile<BM>(B, ldb, k0, Bs);
    __syncthreads();
    h8_t af[4], bf[4];
    #pragma unroll
    for (int mt = 0; mt < 4; mt++)
      af[mt] = *(const h8_t*)(As + ((((wm<<6) + (mt<<4) + l15)) << 5) + (quad << 3));
    #pragma unroll
    for (int nt = 0; nt < 4; nt++)
      bf[nt] = *(const h8_t*)(Bs + ((((wn<<6) + (nt<<4) + l15)) << 5) + (quad << 3));
    #pragma unroll
    for (int mt = 0; mt < 4; mt++)
      #pragma unroll
      for (int nt = 0; nt < 4; nt++)
        acc[mt][nt] = __builtin_amdgcn_mfma_f32_16x16x32_f16(af[mt], bf[nt], acc[mt][nt], 0, 0, 0);
  }
}

#define HG_PROLOG  \
  __shared__ __align__(16) _Float16 As[4096], Bs[4096]; \
  __shared__ float red[256]; \
  f4_t acc[4][4]; \
  { f4_t z = {0.f,0.f,0.f,0.f}; \
    for (int i=0;i<4;i++) for (int j=0;j<4;j++) acc[i][j] = z; } \
  int lane = threadIdx.x & 63, wave = threadIdx.x >> 6; \
  int wm = wave & 1, wn = wave >> 1, quad = lane >> 4, l15 = lane & 15; (void)red;

// C/D lane map (m89-verified): D[row=(quad*4+reg)][col=l15]; row<->A's m, col<->B's n.

// generic f16 NT gemm + optional C-range stats
__global__ __launch_bounds__(256) void k_hgemm_f(const _Float16* __restrict__ A, const _Float16* __restrict__ B,
                                                 float* __restrict__ C, int N, int K,
                                                 unsigned* stats, int slotC){
  HG_PROLOG
  int bm = blockIdx.y << 7, bn = blockIdx.x << 7;
  hgemm_main<0,0>(A + (size_t)bm*K, K, B + (size_t)bn*K, K, K, acc, As, Bs);
  float mn = FLT_MAX, mx = -FLT_MAX;
  #pragma unroll
  for (int mt = 0; mt < 4; mt++)
    #pragma unroll
    for (int nt = 0; nt < 4; nt++){
      int Cc = bn + (wn<<6) + (nt<<4) + l15;
      #pragma unroll
      for (int i = 0; i < 4; i++){
        int R = bm + (wm<<6) + (mt<<4) + (quad<<2) + i;
        float v = acc[mt][nt][i];
        C[(size_t)R*N + Cc] = v;
        mn = fminf(mn, v); mx = fmaxf(mx, v);
      }
    }
  if (slotC >= 0){
    float bmn = bred_min(mn, red), bmx = bred_max(mx, red);
    if (threadIdx.x == 0){ atomicMin(&stats[slotC*16], f2o(bmn)); atomicMax(&stats[(slotC+1)*16], f2o(bmx)); }
  }
}

// fused K/V projections: z=0 -> (Bk, Ck, slot4), z=1 -> (Bv, Cv, slot6)
__global__ __launch_bounds__(256) void k_hgemm_kv(const _Float16* __restrict__ A,
                                                  const _Float16* __restrict__ Bk, const _Float16* __restrict__ Bv,
                                                  float* __restrict__ Ck, float* __restrict__ Cv,
                                                  int K, unsigned* stats){
  HG_PROLOG
  const _Float16* B = blockIdx.z ? Bv : Bk;
  float* C = blockIdx.z ? Cv : Ck;
  int slotC = blockIdx.z ? 6 : 4;
  int bm = blockIdx.y << 7, bn = blockIdx.x << 7;
  hgemm_main<0,0>(A + (size_t)bm*K, K, B + (size_t)bn*K, K, K, acc, As, Bs);
  float mn = FLT_MAX, mx = -FLT_MAX;
  #pragma unroll
  for (int mt = 0; mt < 4; mt++)
    #pragma unroll
    for (int nt = 0; nt < 4; nt++){
      int Cc = bn + (wn<<6) + (nt<<4) + l15;
      #pragma unroll
      for (int i = 0; i < 4; i++){
        int R = bm + (wm<<6) + (mt<<4) + (quad<<2) + i;
        float v = acc[mt][nt][i];
        C[(size_t)R*1024 + Cc] = v;
        mn = fminf(mn, v); mx = fmaxf(mx, v);
      }
    }
  float bmn = bred_min(mn, red), bmx = bred_max(mx, red);
  if (threadIdx.x == 0){ atomicMin(&stats[slotC*16], f2o(bmn)); atomicMax(&stats[(slotC+1)*16], f2o(bmx)); }
}

// QK^T per (b,h): raw logits + global min/max/unmasked-max + per-row min
__global__ __launch_bounds__(256) void k_hgemm_qk(const _Float16* __restrict__ q_h, const _Float16* __restrict__ k_h,
                                                  float* __restrict__ logits, unsigned* stats,
                                                  unsigned* rowmin){
  HG_PROLOG
  int z = blockIdx.z, b = z >> 4, h = z & 15;
  int bm = blockIdx.y << 7, bn = blockIdx.x << 7;
  const _Float16* Ab = q_h + (size_t)z*131072 + (size_t)bm*128;
  const _Float16* Bb = k_h + (size_t)(b*8 + (h>>1))*131072 + (size_t)bn*128;
  hgemm_main<0,0>(Ab, 128, Bb, 128, 128, acc, As, Bs);
  float* Cp = logits + (size_t)z*1048576;
  unsigned* rmz = rowmin + (z << 10);
  float mn = FLT_MAX, mx = -FLT_MAX, mxU = -FLT_MAX;
  #pragma unroll
  for (int mt = 0; mt < 4; mt++){
    int rb = bm + (wm<<6) + (mt<<4) + (quad<<2);
    float rmv[4] = {FLT_MAX, FLT_MAX, FLT_MAX, FLT_MAX};
    #pragma unroll
    for (int nt = 0; nt < 4; nt++){
      int Cc = bn + (wn<<6) + (nt<<4) + l15;
      #pragma unroll
      for (int i = 0; i < 4; i++){
        float v = acc[mt][nt][i];
        Cp[(size_t)(rb + i)*1024 + Cc] = v;
        mn = fminf(mn, v); mx = fmaxf(mx, v);
        if (Cc <= rb + i) mxU = fmaxf(mxU, v);
        rmv[i] = fminf(rmv[i], v);
      }
    }
    #pragma unroll
    for (int d = 1; d < 16; d <<= 1){
      #pragma unroll
      for (int i = 0; i < 4; i++) rmv[i] = fminf(rmv[i], __shfl_xor(rmv[i], d, 64));
    }
    if (l15 == 0){
      #pragma unroll
      for (int i = 0; i < 4; i++) atomicMin(&rmz[rb + i], f2o(rmv[i]));
    }
  }
  float bmn = bred_min(mn, red), bmx = bred_max(mx, red), bmU = bred_max(mxU, red);
  if (threadIdx.x == 0){
    atomicMin(&stats[28*16], f2o(bmn));
    atomicMax(&stats[29*16], f2o(bmx));
    atomicMax(&stats[31*16], f2o(bmU));
  }
}

// PV per (b,h): A = fp32 probs (x1024 in staging), B = vT_h; ctx + stats
__global__ __launch_bounds__(256) void k_hgemm_pv(const float* __restrict__ pat, const _Float16* __restrict__ vT,
                                                  float* __restrict__ ctx, unsigned* stats){
  HG_PROLOG
  int z = blockIdx.z, b = z >> 4, h = z & 15;
  int bm = blockIdx.y << 7;
  const float*    Ab = pat + (size_t)z*1048576 + (size_t)bm*1024;
  const _Float16* Bb = vT + (size_t)(b*8 + (h>>1))*131072;
  hgemm_main<3,0>(Ab, 1024, Bb, 1024, 1024, acc, As, Bs);
  float* Cb = ctx + ((size_t)b << 10)*2048 + (size_t)h*128;
  float mn = FLT_MAX, mx = -FLT_MAX;
  #pragma unroll
  for (int mt = 0; mt < 4; mt++)
    #pragma unroll
    for (int nt = 0; nt < 4; nt++){
      int Cc = (wn<<6) + (nt<<4) + l15;
      #pragma unroll
      for (int i = 0; i < 4; i++){
        int R = bm + (wm<<6) + (mt<<4) + (quad<<2) + i;
        float v = acc[mt][nt][i] * (1.0f/1024.0f);
        Cb[(size_t)R*2048 + Cc] = v;
        mn = fminf(mn, v); mx = fmaxf(mx, v);
      }
    }
  float bmn = bred_min(mn, red), bmx = bred_max(mx, red);
  if (threadIdx.x == 0){ atomicMin(&stats[36*16], f2o(bmn)); atomicMax(&stats[37*16], f2o(bmx)); }
}

// ===========================================================================

// fq16(A) then per-128 rmsnorm; writes (B,NH,S,D) fp32; reduces full+half ranges
__global__ __launch_bounds__(256) void k_rms(const float* __restrict__ lin, float* __restrict__ buf,
                                             const float* __restrict__ gw, unsigned* stats,
                                             int slot_lin, int slot_out, int NHh, int rows){
  FQP pA = fqp(dec_slot(stats, slot_lin), dec_slot(stats, slot_lin+1));
  int lane = threadIdx.x & 63;
  int wv = (blockIdx.x*256 + threadIdx.x) >> 6;
  int nwv = (gridDim.x*256) >> 6;
  float w0 = gw[lane], w1 = gw[lane + 64];
  float fmn = FLT_MAX, fmx = -FLT_MAX, hmn = FLT_MAX, hmx = -FLT_MAX;
  for (int r = wv; r < rows; r += nwv){
    int h = r % NHh; int rem = r / NHh; int s2 = rem & 1023; int b = rem >> 10;
    const float* src = lin + (size_t)r*128;
    float x0 = fqa(src[lane], pA), x1 = fqa(src[lane + 64], pA);
    float ss = x0*x0 + x1*x1;
    #pragma unroll
    for (int m = 1; m < 64; m <<= 1) ss += __shfl_xor(ss, m, 64);
    float rr = 1.0f/sqrtf(ss*(1.0f/128.0f) + 1e-6f);
    float y0 = x0*rr*w0, y1 = x1*rr*w1;
    float* dst = buf + ((size_t)((b*NHh + h) << 10) + s2)*128;
    dst[lane] = y0; dst[lane + 64] = y1;
    fmn = fminf(fmn, fminf(y0, y1)); fmx = fmaxf(fmx, fmaxf(y0, y1));
    hmn = fminf(hmn, y1); hmx = fmaxf(hmx, y1);
  }
  __shared__ float red[256];
  float a = bred_min(fmn, red), bb = bred_max(fmx, red);
  float c = bred_min(hmn, red), d = bred_max(hmx, red);
  if (threadIdx.x == 0){
    atomicMin(&stats[slot_out*16], f2o(a));     atomicMax(&stats[(slot_out+1)*16], f2o(bb));
    atomicMin(&stats[(slot_out+2)*16], f2o(c)); atomicMax(&stats[(slot_out+3)*16], f2o(d));
  }
}

struct RopeQ { FQP B, C, E, F; };
__device__ RopeQ derive_rope(const unsigned* st, int base){
  float ymn = dec_slot(st, base),   ymx = dec_slot(st, base+1);
  float y2mn = dec_slot(st, base+2), y2mx = dec_slot(st, base+3);
  RopeQ r;
  r.B = fqp(ymn, ymx);
  float zmn = fqa(ymn, r.B), zmx = fqa(ymx, r.B);
  r.C = fqp(zmn, zmx);
  float zlo = fqa(zmn, r.C), zhi = fqa(zmx, r.C);
  float z2lo = fqa(fqa(y2mn, r.B), r.C), z2hi = fqa(fqa(y2mx, r.B), r.C);
  r.E = fqp(-z2hi, -z2lo);
  float nlo = fqa(-z2hi, r.E), nhi = fqa(-z2lo, r.E);
  r.F = fqp_raw(fminf(fminf(zlo, nlo), 0.0f), fmaxf(fmaxf(zhi, nhi), 0.0f));
  return r;
}

__global__ __launch_bounds__(256) void k_rope(float* __restrict__ buf, const float* __restrict__ cosp,
                                              const float* __restrict__ sinp, unsigned* stats,
                                              int slot_norm, int slot_prod, int slot_sum,
                                              int NHh, int rows, int do_write){
  RopeQ R = derive_rope(stats, slot_norm);
  FQP pD, pG;
  if (do_write){
    pD = fqp(dec_slot(stats, slot_prod),   dec_slot(stats, slot_prod+1));
    pG = fqp(dec_slot(stats, slot_prod+2), dec_slot(stats, slot_prod+3));
  }
  int lane = threadIdx.x & 63;
  int wv = (blockIdx.x*256 + threadIdx.x) >> 6, nwv = (gridDim.x*256) >> 6;
  float m0 = FLT_MAX, M0 = -FLT_MAX, m1 = FLT_MAX, M1 = -FLT_MAX;
  for (int r = wv; r < rows; r += nwv){
    int s2 = r & 1023; int bh = r >> 10; int b = bh/NHh;
    float* base = buf + (size_t)r*128;
    float y0 = base[lane], y1 = base[lane + 64];
    float z0 = fqa(fqa(y0, R.B), R.C), z1 = fqa(fqa(y1, R.B), R.C);
    const float* cr = cosp + (size_t)((b << 10) + s2)*128;
    const float* sr = sinp + (size_t)((b << 10) + s2)*128;
    float c0 = cr[lane], c1 = cr[lane + 64], sn0 = sr[lane], sn1 = sr[lane + 64];
    float pc0 = z0*c0, pc1 = z1*c1;
    float rh0 = fqa(fqa(-z1, R.E), R.F);
    float rh1 = fqa(z0, R.F);
    float ps0 = rh0*sn0, ps1 = rh1*sn1;
    if (!do_write){
      m0 = fminf(m0, fminf(pc0, pc1)); M0 = fmaxf(M0, fmaxf(pc0, pc1));
      m1 = fminf(m1, fminf(ps0, ps1)); M1 = fmaxf(M1, fmaxf(ps0, ps1));
    } else {
      float sv0 = fqa(pc0, pD) + fqa(ps0, pG);
      float sv1 = fqa(pc1, pD) + fqa(ps1, pG);
      base[lane] = sv0; base[lane + 64] = sv1;
      m0 = fminf(m0, fminf(sv0, sv1)); M0 = fmaxf(M0, fmaxf(sv0, sv1));
    }
  }
  __shared__ float red[256];
  if (!do_write){
    float a = bred_min(m0, red), bb = bred_max(M0, red);
    float c = bred_min(m1, red), d = bred_max(M1, red);
    if (threadIdx.x == 0){
      atomicMin(&stats[slot_prod*16], f2o(a));     atomicMax(&stats[(slot_prod+1)*16], f2o(bb));
      atomicMin(&stats[(slot_prod+2)*16], f2o(c)); atomicMax(&stats[(slot_prod+3)*16], f2o(d));
    }
  } else {
    float a = bred_min(m0, red), bb = bred_max(M0, red);
    if (threadIdx.x == 0){ atomicMin(&stats[slot_sum*16], f2o(a)); atomicMax(&stats[(slot_sum+1)*16], f2o(bb)); }
  }
}

// V transpose + fq8(fq16) -> f16: vT[b][kv][d][t]
__global__ __launch_bounds__(256) void k_vT(const float* __restrict__ vlin, _Float16* __restrict__ vT,
                                            const unsigned* stats){
  FQP pv = fqp(dec_slot(stats, 6), dec_slot(stats, 7));
  float vlo = fqa(dec_slot(stats, 6), pv), vhi = fqa(dec_slot(stats, 7), pv);
  float v8s = fmaxf(fmaxf(fabsf(vlo), fabsf(vhi))/127.0f, 1e-12f), v8si = 1.0f/v8s;
  __shared__ float tile[64][65];
  int bkv = blockIdx.z, t0 = blockIdx.x << 6, d0 = blockIdx.y << 6;
  int b = bkv >> 3, kv = bkv & 7;
  const float* src = vlin + ((size_t)(b << 10))*1024 + (size_t)kv*128;
  int tx = threadIdx.x & 63, tq = threadIdx.x >> 6;
  #pragma unroll
  for (int i = 0; i < 16; i++){
    int tt = (i << 2) + tq;
    float x = src[(size_t)(t0 + tt)*1024 + d0 + tx];
    tile[tx][tt] = fq8(fqa(x, pv), v8s, v8si);
  }
  __syncthreads();
  _Float16* dst = vT + (size_t)bkv*131072;
  #pragma unroll
  for (int i = 0; i < 16; i++){
    int dd = (i << 2) + tq;
    dst[(size_t)(d0 + dd)*1024 + t0 + tx] = (_Float16)tile[dd][tx];
  }
}

__global__ __launch_bounds__(256) void k_rowstat_m2(const unsigned* __restrict__ rowmin, unsigned* stats, int n){
  float lm = -FLT_MAX;
  for (int i = threadIdx.x; i < n; i += 256) lm = fmaxf(lm, o2f(rowmin[i]));
  __shared__ float red[256];
  float m = bred_max(lm, red);
  if (threadIdx.x == 0) stats[35*16] = f2o(m);
}
__global__ __launch_bounds__(256) void k_denom_min(const float* __restrict__ denomS, unsigned* stats, int n){
  float lm = FLT_MAX;
  for (int i = threadIdx.x; i < n; i += 256) lm = fminf(lm, denomS[i]);
  __shared__ float red[256];
  float m = bred_min(lm, red);
  if (threadIdx.x == 0) stats[32*16] = f2o(m);
}

struct LogitQ { FQP f1, f2, fam, fvv, f3; float sc, c20; };
__device__ LogitQ derive_logit(const unsigned* st){
  LogitQ L;
  FQP ps = fqp(SCALING_F, SCALING_F); L.sc = fqa(SCALING_F, ps);
  FQP p20 = fqp(-20.0f, -20.0f);      L.c20 = fqa(-20.0f, p20);
  float gmn = dec_slot(st, 28), gmx = dec_slot(st, 29);
  float gU = dec_slot(st, 31), M2 = dec_slot(st, 35);
  L.f1 = fqp(gmn, gmx);
  float l1lo = fqa(gmn, L.f1), l1hi = fqa(gmx, L.f1);
  L.f2 = fqp(l1lo*L.sc, l1hi*L.sc);
  float amlo = fqa(fqa(gmn, L.f1)*L.sc, L.f2);
  float amhi = fqa(fqa(M2, L.f1)*L.sc, L.f2);
  L.fam = fqp(amlo, amhi);
  float vslo = fqa(amlo, L.fam) + L.c20, vshi = fqa(amhi, L.fam) + L.c20;
  L.fvv = fqp(vslo, vshi);
  float mn3 = fqa(vslo, L.fvv);
  float mx3 = fqa(fqa(gU, L.f1)*L.sc, L.f2);
  L.f3 = fqp(mn3, mx3);
  return L;
}
__device__ __forceinline__ float masked_a3(float raw, int t, int s, const LogitQ& L, float vv3){
  float a2 = fqa(fqa(raw, L.f1)*L.sc, L.f2);
  return (t <= s) ? fqa(a2, L.f3) : vv3;
}
__device__ __forceinline__ float row_vv3(const unsigned* rowmin, int row, const LogitQ& L){
  float tr = fqa(fqa(o2f(rowmin[row]), L.f1)*L.sc, L.f2);
  return fqa(fqa(fqa(tr, L.fam) + L.c20, L.fvv), L.f3);
}

__global__ __launch_bounds__(256) void k_softmax_stats(const float* __restrict__ logits,
                                                       const unsigned* __restrict__ rowmin,
                                                       float* __restrict__ mS, float* __restrict__ denomS,
                                                       const unsigned* stats){
  LogitQ L = derive_logit(stats);
  int row = blockIdx.x; int s = row & 1023;
  float vv3 = row_vv3(rowmin, row, L);
  const float* rp = logits + (size_t)row*S_LEN;
  int tid = threadIdx.x;
  float vals[4]; float lm = -FLT_MAX;
  #pragma unroll
  for (int i = 0; i < 4; i++){
    int t = (i << 8) + tid;
    vals[i] = masked_a3(rp[t], t, s, L, vv3);
    lm = fmaxf(lm, vals[i]);
  }
  __shared__ float red[256];
  float m = bred_max(lm, red);
  float ls = 0.0f;
  #pragma unroll
  for (int i = 0; i < 4; i++) ls += expf(vals[i] - m);
  float dn = bred_sum(ls, red);
  if (tid == 0){ mS[row] = m; denomS[row] = dn; }
}

__global__ __launch_bounds__(256) void k_softmax_write(float* __restrict__ logits,
                                                       const unsigned* __restrict__ rowmin,
                                                       const float* __restrict__ mS,
                                                       const float* __restrict__ denomS,
                                                       const unsigned* stats){
  LogitQ L = derive_logit(stats);
  float maxp = 1.0f/dec_slot(stats, 32);
  FQP p4 = fqp(0.0f, maxp);
  int row = blockIdx.x; int s = row & 1023;
  float vv3 = row_vv3(rowmin, row, L);
  float m = mS[row], dn = denomS[row];
  float* rp = logits + (size_t)row*S_LEN;
  int tid = threadIdx.x;
  #pragma unroll
  for (int i = 0; i < 4; i++){
    int t = (i << 8) + tid;
    float a3 = masked_a3(rp[t], t, s, L, vv3);
    float p = expf(a3 - m)/dn;
    rp[t] = fqa(p, p4);
  }
}

extern "C" void kernel_launch(void* const* d_in, const int* in_sizes, int n_in,
                              void* d_out, int out_size, void* d_ws, size_t ws_size,
                              hipStream_t stream){
  (void)in_sizes; (void)n_in; (void)out_size; (void)ws_size;
  const float* hs   = (const float*)d_in[0];
  const float* cosp = (const float*)d_in[1];
  const float* sinp = (const float*)d_in[2];
  const float* Wq   = (const float*)d_in[4];
  const float* Wk   = (const float*)d_in[5];
  const float* Wv   = (const float*)d_in[6];
  const float* Wo   = (const float*)d_in[7];
  const float* qnw  = (const float*)d_in[8];
  const float* knw  = (const float*)d_in[9];

  float* outp = (float*)d_out;
  float* attn = outp + 4194304;      // raw logits, then final quantized softmax

  const size_t MEG = 1u << 20;       // floats
  float* wsf = (float*)d_ws;
  _Float16* woq_h = (_Float16*)(wsf + 0);
  _Float16* wqq_h = (_Float16*)(wsf + 2*MEG);
  _Float16* wkq_h = (_Float16*)(wsf + 4*MEG);
  _Float16* wvq_h = (_Float16*)(wsf + 5*MEG);
  _Float16* hsq_h = (_Float16*)(wsf + 6*MEG);
  float* qlin = wsf + 8*MEG;  float* ctx = qlin;   // ctx reuses qlin
  float* klin = wsf + 12*MEG;
  float* vlin = wsf + 14*MEG;
  float* qbuf = wsf + 16*MEG;
  float* kbuf = wsf + 20*MEG;
  _Float16* q_h   = (_Float16*)(wsf + 22*MEG);
  _Float16* k_h   = (_Float16*)(wsf + 24*MEG);
  _Float16* vT_h  = (_Float16*)(wsf + 25*MEG);
  _Float16* ctx_h = (_Float16*)(wsf + 26*MEG);
  unsigned* rowmin = (unsigned*)(wsf + 28*MEG);
  float* mS     = wsf + 28*MEG + 32768;
  float* denomS = wsf + 28*MEG + 65536;
  unsigned* stats = (unsigned*)(wsf + 28*MEG + 98304);
  // ws usage ~112.4 MB

  k_init<<<128, 256, 0, stream>>>(stats, rowmin, 32768);

  k_quantw<<<4096, 256, 0, stream>>>(Wq, wqq_h);
  k_quantw<<<2048, 256, 0, stream>>>(Wk, wkq_h);
  k_quantw<<<2048, 256, 0, stream>>>(Wv, wvq_h);
  k_quantw<<<4096, 256, 0, stream>>>(Wo, woq_h);

  k_minmax<<<1024, 256, 0, stream>>>(hs, 4194304, stats, 0);
  k_fq_ew16<<<4096, 256, 0, stream>>>(hs, hsq_h, stats, 0);

  // projections (f16 MFMA), raw-output range stats in epilogue
  k_hgemm_f<<<dim3(16, 16), 256, 0, stream>>>(hsq_h, wqq_h, qlin, 2048, 2048, stats, 2);
  k_hgemm_kv<<<dim3(8, 16, 2), 256, 0, stream>>>(hsq_h, wkq_h, wvq_h, klin, vlin, 2048, stats);

  // fq16 + rmsnorm (fp32) + range reductions
  k_rms<<<1024, 256, 0, stream>>>(qlin, qbuf, qnw, stats, 2, 8, 16, 32768);
  k_rms<<<512, 256, 0, stream>>>(klin, kbuf, knw, stats, 4, 12, 8, 16384);

  // RoPE: range pass then write pass
  k_rope<<<1024, 256, 0, stream>>>(qbuf, cosp, sinp, stats, 8, 16, 24, 16, 32768, 0);
  k_rope<<<512, 256, 0, stream>>>(kbuf, cosp, sinp, stats, 12, 20, 26, 8, 16384, 0);
  k_rope<<<1024, 256, 0, stream>>>(qbuf, cosp, sinp, stats, 8, 16, 24, 16, 32768, 1);
  k_rope<<<512, 256, 0, stream>>>(kbuf, cosp, sinp, stats, 12, 20, 26, 8, 16384, 1);

  // operand conversion for QK (fq16 -> f16, fq8(fq16) -> f16) and V transpose
  k_fq_ew16<<<4096, 256, 0, stream>>>(qbuf, q_h, stats, 24);
  k_fq8_ew16<<<2048, 256, 0, stream>>>(kbuf, k_h, stats, 26);
  k_vT<<<dim3(16, 2, 16), 256, 0, stream>>>(vlin, vT_h, stats);

  // QK^T raw logits (d_out attn region) + logit stats + per-row mins
  k_hgemm_qk<<<dim3(8, 8, 32), 256, 0, stream>>>(q_h, k_h, attn, stats, rowmin);
  k_rowstat_m2<<<1, 256, 0, stream>>>(rowmin, stats, 32768);

  // softmax: stats pass, global denom-min, quantized write in place
  k_softmax_stats<<<32768, 256, 0, stream>>>(attn, rowmin, mS, denomS, stats);
  k_denom_min<<<1, 256, 0, stream>>>(denomS, stats, 32768);
  k_softmax_write<<<32768, 256, 0, stream>>>(attn, rowmin, mS, denomS, stats);

  // PV (f16 MFMA, probs staged x1024) -> ctx + stats; then fq16 -> f16; O-proj
  k_hgemm_pv<<<dim3(1, 8, 32), 256, 0, stream>>>(attn, vT_h, ctx, stats);
  k_fq_ew16<<<4096, 256, 0, stream>>>(ctx, ctx_h, stats, 36);
  k_hgemm_f<<<dim3(16, 16), 256, 0, stream>>>(ctx_h, woq_h, outp, 2048, 2048, stats, -1);
}

// Round 3
// 784.490 us; speedup vs baseline: 2.2916x; 1.0526x over previous
//
#include <hip/hip_runtime.h>
#include <cfloat>
#include <cmath>

// ---------------------------------------------------------------------------
// Qwen3Attention fake-quant forward. B=2 S=1024 HID=2048 NH=16 NKV=8 D=128.
// Round 3: f16 MFMA GEMMs (16x16x32). Softmax restructured:
//   - per-row unmasked max tracked in QK epilogue -> m analytic per row
//   - single denom pass (fast __expf)
//   - final prob + fq16 + attn-output write FUSED into PV A-staging
// ---------------------------------------------------------------------------

#define FQ_EPS      1.5259021896696422e-09f   // 0.0001/65535
#define SCALING_F   0.08838834764831845f      // 128**-0.5
#define S_LEN       1024

typedef _Float16 h8_t __attribute__((ext_vector_type(8)));
typedef _Float16 h4_t __attribute__((ext_vector_type(4)));
typedef float    f4_t __attribute__((ext_vector_type(4)));

// ---- float <-> order-preserving unsigned encoding (for atomic min/max) ----
__device__ __forceinline__ unsigned f2o(float f){
  unsigned u = __float_as_uint(f);
  return (u & 0x80000000u) ? ~u : (u | 0x80000000u);
}
__device__ __forceinline__ float o2f(unsigned u){
  return __uint_as_float((u & 0x80000000u) ? (u ^ 0x80000000u) : ~u);
}
__device__ __forceinline__ float dec_slot(const unsigned* st, int s){ return o2f(st[s*16]); }

// ---- fq16 helpers ----
struct FQP { float scale, zp, inv; };
__device__ __forceinline__ FQP fqp_raw(float mn, float mx){
  FQP p; p.scale = fmaxf((mx - mn)/65535.0f, FQ_EPS); p.zp = rintf(-mn/p.scale);
  p.inv = 1.0f/p.scale; return p;
}
__device__ __forceinline__ FQP fqp(float mn0, float mx0){
  return fqp_raw(fminf(mn0, 0.0f), fmaxf(mx0, 0.0f));
}
__device__ __forceinline__ float fqa(float x, FQP p){
  float q = rintf(x*p.inv) + p.zp;
  q = fminf(fmaxf(q, 0.0f), 65535.0f);
  return (q - p.zp)*p.scale;
}
__device__ __forceinline__ float fq8(float x, float s, float si){
  return fminf(fmaxf(rintf(x*si), -128.0f), 127.0f)*s;
}

// ---- block reductions (blockDim == 256) ----
__device__ __forceinline__ float bred_min(float v, float* red){
  int tid = threadIdx.x; red[tid] = v; __syncthreads();
  for (int s = 128; s > 0; s >>= 1){ if (tid < s) red[tid] = fminf(red[tid], red[tid+s]); __syncthreads(); }
  float r = red[0]; __syncthreads(); return r;
}
__device__ __forceinline__ float bred_max(float v, float* red){
  int tid = threadIdx.x; red[tid] = v; __syncthreads();
  for (int s = 128; s > 0; s >>= 1){ if (tid < s) red[tid] = fmaxf(red[tid], red[tid+s]); __syncthreads(); }
  float r = red[0]; __syncthreads(); return r;
}
__device__ __forceinline__ float bred_sum(float v, float* red){
  int tid = threadIdx.x; red[tid] = v; __syncthreads();
  for (int s = 128; s > 0; s >>= 1){ if (tid < s) red[tid] = red[tid] + red[tid+s]; __syncthreads(); }
  float r = red[0]; __syncthreads(); return r;
}

// ---- stats slot map (even=min, odd=max) ----
// 0/1 hs | 2/3 qlin | 4/5 klin | 6/7 vlin | 8/9 qn | 10/11 qn2 | 12/13 kn | 14/15 kn2
// 16/17 q*c | 18/19 qrh*s | 20/21 k*c | 22/23 krh*s | 24/25 qsum | 26/27 ksum
// 28/29 logits | 31 unmaskedMax | 32 denomMin | 35 maxOfRowMins | 36/37 ctx

__global__ void k_init(unsigned* stats, unsigned* rowmin, unsigned* rowmax, int nrows){
  int i = blockIdx.x*blockDim.x + threadIdx.x;
  if (i < 1024) stats[i] = (((i & 15) == 0) && (((i >> 4) & 1) == 0)) ? 0xFFFFFFFFu : 0u;
  if (i < nrows){ rowmin[i] = 0xFFFFFFFFu; rowmax[i] = 0u; }
}

// lpbq weight quantization -> f16. 4 elems/thread; 8-lane shfl = 32-elem block.
__global__ __launch_bounds__(256) void k_quantw(const float* __restrict__ W, _Float16* __restrict__ Wh){
  int i = blockIdx.x*256 + threadIdx.x;
  float4 v = ((const float4*)W)[i];
  float am = fmaxf(fmaxf(fabsf(v.x), fabsf(v.y)), fmaxf(fabsf(v.z), fabsf(v.w)));
  #pragma unroll
  for (int m = 1; m < 8; m <<= 1) am = fmaxf(am, __shfl_xor(am, m, 64));
  float s = fmaxf(am/7.0f, 1e-12f), si = 1.0f/s;
  h4_t o;
  o[0] = (_Float16)(fminf(fmaxf(rintf(v.x*si), -8.0f), 7.0f)*s);
  o[1] = (_Float16)(fminf(fmaxf(rintf(v.y*si), -8.0f), 7.0f)*s);
  o[2] = (_Float16)(fminf(fmaxf(rintf(v.z*si), -8.0f), 7.0f)*s);
  o[3] = (_Float16)(fminf(fmaxf(rintf(v.w*si), -8.0f), 7.0f)*s);
  *(h4_t*)(Wh + ((size_t)i << 2)) = o;
}

__global__ __launch_bounds__(256) void k_minmax(const float* __restrict__ x, int n, unsigned* stats, int slot){
  float mn = FLT_MAX, mx = -FLT_MAX;
  for (int i = blockIdx.x*256 + threadIdx.x; i < n; i += gridDim.x*256){
    float v = x[i]; mn = fminf(mn, v); mx = fmaxf(mx, v);
  }
  __shared__ float red[256];
  float bmn = bred_min(mn, red), bmx = bred_max(mx, red);
  if (threadIdx.x == 0){ atomicMin(&stats[slot*16], f2o(bmn)); atomicMax(&stats[(slot+1)*16], f2o(bmx)); }
}

// fq16 elementwise -> f16, 4 elems/thread
__global__ __launch_bounds__(256) void k_fq_ew16(const float* __restrict__ x, _Float16* __restrict__ y,
                                                 const unsigned* stats, int slot){
  FQP p = fqp(dec_slot(stats, slot), dec_slot(stats, slot+1));
  int i = blockIdx.x*256 + threadIdx.x;
  float4 v = ((const float4*)x)[i];
  h4_t o;
  o[0] = (_Float16)fqa(v.x, p); o[1] = (_Float16)fqa(v.y, p);
  o[2] = (_Float16)fqa(v.z, p); o[3] = (_Float16)fqa(v.w, p);
  *(h4_t*)(y + ((size_t)i << 2)) = o;
}

// fq8(fq16(x)) elementwise -> f16 (for K)
__global__ __launch_bounds__(256) void k_fq8_ew16(const float* __restrict__ x, _Float16* __restrict__ y,
                                                  const unsigned* stats, int slot){
  FQP p = fqp(dec_slot(stats, slot), dec_slot(stats, slot+1));
  float lo = fqa(dec_slot(stats, slot), p), hi = fqa(dec_slot(stats, slot+1), p);
  float s8 = fmaxf(fmaxf(fabsf(lo), fabsf(hi))/127.0f, 1e-12f), s8i = 1.0f/s8;
  int i = blockIdx.x*256 + threadIdx.x;
  float4 v = ((const float4*)x)[i];
  h4_t o;
  o[0] = (_Float16)fq8(fqa(v.x, p), s8, s8i); o[1] = (_Float16)fq8(fqa(v.y, p), s8, s8i);
  o[2] = (_Float16)fq8(fqa(v.z, p), s8, s8i); o[3] = (_Float16)fq8(fqa(v.w, p), s8, s8i);
  *(h4_t*)(y + ((size_t)i << 2)) = o;
}

// ======================= f16 MFMA GEMM core (NT) ===========================
// 128x128 tile, BK=32, 4 waves (2x2), each wave 64x64 = 4x4 frags of 16x16x32.
__device__ __forceinline__ void stage_tile(const _Float16* __restrict__ src, int ld, int k0,
                                           _Float16* __restrict__ dst){
  #pragma unroll
  for (int it = 0; it < 2; it++){
    int c = threadIdx.x + (it << 8);
    int row = c >> 2, off = (c & 3) << 3;
    const _Float16* sp = src + (size_t)row*ld + k0 + off;
    *(h8_t*)(dst + (c << 3)) = *(const h8_t*)sp;
  }
}

__device__ __forceinline__ void hgemm_main(const _Float16* __restrict__ A, int lda,
                                           const _Float16* __restrict__ B, int ldb, int K,
                                           f4_t acc[4][4], _Float16* As, _Float16* Bs){
  int lane = threadIdx.x & 63, wave = threadIdx.x >> 6;
  int wm = wave & 1, wn = wave >> 1, quad = lane >> 4, l15 = lane & 15;
  for (int k0 = 0; k0 < K; k0 += 32){
    __syncthreads();
    stage_tile(A, lda, k0, As);
    stage_tile(B, ldb, k0, Bs);
    __syncthreads();
    h8_t af[4], bf[4];
    #pragma unroll
    for (int mt = 0; mt < 4; mt++)
      af[mt] = *(const h8_t*)(As + ((((wm<<6) + (mt<<4) + l15)) << 5) + (quad << 3));
    #pragma unroll
    for (int nt = 0; nt < 4; nt++)
      bf[nt] = *(const h8_t*)(Bs + ((((wn<<6) + (nt<<4) + l15)) << 5) + (quad << 3));
    #pragma unroll
    for (int mt = 0; mt < 4; mt++)
      #pragma unroll
      for (int nt = 0; nt < 4; nt++)
        acc[mt][nt] = __builtin_amdgcn_mfma_f32_16x16x32_f16(af[mt], bf[nt], acc[mt][nt], 0, 0, 0);
  }
}

#define HG_PROLOG  \
  __shared__ __align__(16) _Float16 As[4096], Bs[4096]; \
  __shared__ float red[256]; \
  f4_t acc[4][4]; \
  { f4_t zz = {0.f,0.f,0.f,0.f}; \
    for (int i=0;i<4;i++) for (int j=0;j<4;j++) acc[i][j] = zz; } \
  int lane = threadIdx.x & 63, wave = threadIdx.x >> 6; \
  int wm = wave & 1, wn = wave >> 1, quad = lane >> 4, l15 = lane & 15; (void)red;

// C/D lane map (m89-verified): D[row=(quad*4+reg)][col=l15].

__global__ __launch_bounds__(256) void k_hgemm_f(const _Float16* __restrict__ A, const _Float16* __restrict__ B,
                                                 float* __restrict__ C, int N, int K,
                                                 unsigned* stats, int slotC){
  HG_PROLOG
  int bm = blockIdx.y << 7, bn = blockIdx.x << 7;
  hgemm_main(A + (size_t)bm*K, K, B + (size_t)bn*K, K, K, acc, As, Bs);
  float mn = FLT_MAX, mx = -FLT_MAX;
  #pragma unroll
  for (int mt = 0; mt < 4; mt++)
    #pragma unroll
    for (int nt = 0; nt < 4; nt++){
      int Cc = bn + (wn<<6) + (nt<<4) + l15;
      #pragma unroll
      for (int i = 0; i < 4; i++){
        int R = bm + (wm<<6) + (mt<<4) + (quad<<2) + i;
        float v = acc[mt][nt][i];
        C[(size_t)R*N + Cc] = v;
        mn = fminf(mn, v); mx = fmaxf(mx, v);
      }
    }
  if (slotC >= 0){
    float bmn = bred_min(mn, red), bmx = bred_max(mx, red);
    if (threadIdx.x == 0){ atomicMin(&stats[slotC*16], f2o(bmn)); atomicMax(&stats[(slotC+1)*16], f2o(bmx)); }
  }
}

// fused K/V projections: z=0 -> (Bk, Ck, slot4), z=1 -> (Bv, Cv, slot6)
__global__ __launch_bounds__(256) void k_hgemm_kv(const _Float16* __restrict__ A,
                                                  const _Float16* __restrict__ Bk, const _Float16* __restrict__ Bv,
                                                  float* __restrict__ Ck, float* __restrict__ Cv,
                                                  int K, unsigned* stats){
  HG_PROLOG
  const _Float16* B = blockIdx.z ? Bv : Bk;
  float* C = blockIdx.z ? Cv : Ck;
  int slotC = blockIdx.z ? 6 : 4;
  int bm = blockIdx.y << 7, bn = blockIdx.x << 7;
  hgemm_main(A + (size_t)bm*K, K, B + (size_t)bn*K, K, K, acc, As, Bs);
  float mn = FLT_MAX, mx = -FLT_MAX;
  #pragma unroll
  for (int mt = 0; mt < 4; mt++)
    #pragma unroll
    for (int nt = 0; nt < 4; nt++){
      int Cc = bn + (wn<<6) + (nt<<4) + l15;
      #pragma unroll
      for (int i = 0; i < 4; i++){
        int R = bm + (wm<<6) + (mt<<4) + (quad<<2) + i;
        float v = acc[mt][nt][i];
        C[(size_t)R*1024 + Cc] = v;
        mn = fminf(mn, v); mx = fmaxf(mx, v);
      }
    }
  float bmn = bred_min(mn, red), bmx = bred_max(mx, red);
  if (threadIdx.x == 0){ atomicMin(&stats[slotC*16], f2o(bmn)); atomicMax(&stats[(slotC+1)*16], f2o(bmx)); }
}

// QK^T per (b,h): raw logits + global min/max/unmasked-max + per-row min AND
// per-row unmasked max (for analytic softmax m).
__global__ __launch_bounds__(256) void k_hgemm_qk(const _Float16* __restrict__ q_h, const _Float16* __restrict__ k_h,
                                                  float* __restrict__ logits, unsigned* stats,
                                                  unsigned* rowmin, unsigned* rowmax){
  HG_PROLOG
  int z = blockIdx.z, b = z >> 4, h = z & 15;
  int bm = blockIdx.y << 7, bn = blockIdx.x << 7;
  const _Float16* Ab = q_h + (size_t)z*131072 + (size_t)bm*128;
  const _Float16* Bb = k_h + (size_t)(b*8 + (h>>1))*131072 + (size_t)bn*128;
  hgemm_main(Ab, 128, Bb, 128, 128, acc, As, Bs);
  float* Cp = logits + (size_t)z*1048576;
  unsigned* rmz = rowmin + (z << 10);
  unsigned* rxz = rowmax + (z << 10);
  float mn = FLT_MAX, mx = -FLT_MAX, mxU = -FLT_MAX;
  #pragma unroll
  for (int mt = 0; mt < 4; mt++){
    int rb = bm + (wm<<6) + (mt<<4) + (quad<<2);
    float rmv[4] = {FLT_MAX, FLT_MAX, FLT_MAX, FLT_MAX};
    float rxv[4] = {-FLT_MAX, -FLT_MAX, -FLT_MAX, -FLT_MAX};
    #pragma unroll
    for (int nt = 0; nt < 4; nt++){
      int Cc = bn + (wn<<6) + (nt<<4) + l15;
      #pragma unroll
      for (int i = 0; i < 4; i++){
        float v = acc[mt][nt][i];
        Cp[(size_t)(rb + i)*1024 + Cc] = v;
        mn = fminf(mn, v); mx = fmaxf(mx, v);
        rmv[i] = fminf(rmv[i], v);
        if (Cc <= rb + i){ mxU = fmaxf(mxU, v); rxv[i] = fmaxf(rxv[i], v); }
      }
    }
    #pragma unroll
    for (int d = 1; d < 16; d <<= 1){
      #pragma unroll
      for (int i = 0; i < 4; i++){
        rmv[i] = fminf(rmv[i], __shfl_xor(rmv[i], d, 64));
        rxv[i] = fmaxf(rxv[i], __shfl_xor(rxv[i], d, 64));
      }
    }
    if (l15 == 0){
      #pragma unroll
      for (int i = 0; i < 4; i++){
        atomicMin(&rmz[rb + i], f2o(rmv[i]));
        atomicMax(&rxz[rb + i], f2o(rxv[i]));
      }
    }
  }
  float bmn = bred_min(mn, red), bmx = bred_max(mx, red), bmU = bred_max(mxU, red);
  if (threadIdx.x == 0){
    atomicMin(&stats[28*16], f2o(bmn));
    atomicMax(&stats[29*16], f2o(bmx));
    atomicMax(&stats[31*16], f2o(bmU));
  }
}

// ===========================================================================

// fq16(A) then per-128 rmsnorm; writes (B,NH,S,D) fp32; reduces full+half ranges
__global__ __launch_bounds__(256) void k_rms(const float* __restrict__ lin, float* __restrict__ buf,
                                             const float* __restrict__ gw, unsigned* stats,
                                             int slot_lin, int slot_out, int NHh, int rows){
  FQP pA = fqp(dec_slot(stats, slot_lin), dec_slot(stats, slot_lin+1));
  int lane = threadIdx.x & 63;
  int wv = (blockIdx.x*256 + threadIdx.x) >> 6;
  int nwv = (gridDim.x*256) >> 6;
  float w0 = gw[lane], w1 = gw[lane + 64];
  float fmn = FLT_MAX, fmx = -FLT_MAX, hmn = FLT_MAX, hmx = -FLT_MAX;
  for (int r = wv; r < rows; r += nwv){
    int h = r % NHh; int rem = r / NHh; int s2 = rem & 1023; int b = rem >> 10;
    const float* src = lin + (size_t)r*128;
    float x0 = fqa(src[lane], pA), x1 = fqa(src[lane + 64], pA);
    float ss = x0*x0 + x1*x1;
    #pragma unroll
    for (int m = 1; m < 64; m <<= 1) ss += __shfl_xor(ss, m, 64);
    float rr = 1.0f/sqrtf(ss*(1.0f/128.0f) + 1e-6f);
    float y0 = x0*rr*w0, y1 = x1*rr*w1;
    float* dst = buf + ((size_t)((b*NHh + h) << 10) + s2)*128;
    dst[lane] = y0; dst[lane + 64] = y1;
    fmn = fminf(fmn, fminf(y0, y1)); fmx = fmaxf(fmx, fmaxf(y0, y1));
    hmn = fminf(hmn, y1); hmx = fmaxf(hmx, y1);
  }
  __shared__ float red[256];
  float a = bred_min(fmn, red), bb = bred_max(fmx, red);
  float c = bred_min(hmn, red), d = bred_max(hmx, red);
  if (threadIdx.x == 0){
    atomicMin(&stats[slot_out*16], f2o(a));     atomicMax(&stats[(slot_out+1)*16], f2o(bb));
    atomicMin(&stats[(slot_out+2)*16], f2o(c)); atomicMax(&stats[(slot_out+3)*16], f2o(d));
  }
}

struct RopeQ { FQP B, C, E, F; };
__device__ RopeQ derive_rope(const unsigned* st, int base){
  float ymn = dec_slot(st, base),   ymx = dec_slot(st, base+1);
  float y2mn = dec_slot(st, base+2), y2mx = dec_slot(st, base+3);
  RopeQ r;
  r.B = fqp(ymn, ymx);
  float zmn = fqa(ymn, r.B), zmx = fqa(ymx, r.B);
  r.C = fqp(zmn, zmx);
  float zlo = fqa(zmn, r.C), zhi = fqa(zmx, r.C);
  float z2lo = fqa(fqa(y2mn, r.B), r.C), z2hi = fqa(fqa(y2mx, r.B), r.C);
  r.E = fqp(-z2hi, -z2lo);
  float nlo = fqa(-z2hi, r.E), nhi = fqa(-z2lo, r.E);
  r.F = fqp_raw(fminf(fminf(zlo, nlo), 0.0f), fmaxf(fmaxf(zhi, nhi), 0.0f));
  return r;
}

__global__ __launch_bounds__(256) void k_rope(float* __restrict__ buf, const float* __restrict__ cosp,
                                              const float* __restrict__ sinp, unsigned* stats,
                                              int slot_norm, int slot_prod, int slot_sum,
                                              int NHh, int rows, int do_write){
  RopeQ R = derive_rope(stats, slot_norm);
  FQP pD, pG;
  if (do_write){
    pD = fqp(dec_slot(stats, slot_prod),   dec_slot(stats, slot_prod+1));
    pG = fqp(dec_slot(stats, slot_prod+2), dec_slot(stats, slot_prod+3));
  }
  int lane = threadIdx.x & 63;
  int wv = (blockIdx.x*256 + threadIdx.x) >> 6, nwv = (gridDim.x*256) >> 6;
  float m0 = FLT_MAX, M0 = -FLT_MAX, m1 = FLT_MAX, M1 = -FLT_MAX;
  for (int r = wv; r < rows; r += nwv){
    int s2 = r & 1023; int bh = r >> 10; int b = bh/NHh;
    float* base = buf + (size_t)r*128;
    float y0 = base[lane], y1 = base[lane + 64];
    float z0 = fqa(fqa(y0, R.B), R.C), z1 = fqa(fqa(y1, R.B), R.C);
    const float* cr = cosp + (size_t)((b << 10) + s2)*128;
    const float* sr = sinp + (size_t)((b << 10) + s2)*128;
    float c0 = cr[lane], c1 = cr[lane + 64], sn0 = sr[lane], sn1 = sr[lane + 64];
    float pc0 = z0*c0, pc1 = z1*c1;
    float rh0 = fqa(fqa(-z1, R.E), R.F);
    float rh1 = fqa(z0, R.F);
    float ps0 = rh0*sn0, ps1 = rh1*sn1;
    if (!do_write){
      m0 = fminf(m0, fminf(pc0, pc1)); M0 = fmaxf(M0, fmaxf(pc0, pc1));
      m1 = fminf(m1, fminf(ps0, ps1)); M1 = fmaxf(M1, fmaxf(ps0, ps1));
    } else {
      float sv0 = fqa(pc0, pD) + fqa(ps0, pG);
      float sv1 = fqa(pc1, pD) + fqa(ps1, pG);
      base[lane] = sv0; base[lane + 64] = sv1;
      m0 = fminf(m0, fminf(sv0, sv1)); M0 = fmaxf(M0, fmaxf(sv0, sv1));
    }
  }
  __shared__ float red[256];
  if (!do_write){
    float a = bred_min(m0, red), bb = bred_max(M0, red);
    float c = bred_min(m1, red), d = bred_max(M1, red);
    if (threadIdx.x == 0){
      atomicMin(&stats[slot_prod*16], f2o(a));     atomicMax(&stats[(slot_prod+1)*16], f2o(bb));
      atomicMin(&stats[(slot_prod+2)*16], f2o(c)); atomicMax(&stats[(slot_prod+3)*16], f2o(d));
    }
  } else {
    float a = bred_min(m0, red), bb = bred_max(M0, red);
    if (threadIdx.x == 0){ atomicMin(&stats[slot_sum*16], f2o(a)); atomicMax(&stats[(slot_sum+1)*16], f2o(bb)); }
  }
}

// V transpose + fq8(fq16) -> f16: vT[b][kv][d][t]
__global__ __launch_bounds__(256) void k_vT(const float* __restrict__ vlin, _Float16* __restrict__ vT,
                                            const unsigned* stats){
  FQP pv = fqp(dec_slot(stats, 6), dec_slot(stats, 7));
  float vlo = fqa(dec_slot(stats, 6), pv), vhi = fqa(dec_slot(stats, 7), pv);
  float v8s = fmaxf(fmaxf(fabsf(vlo), fabsf(vhi))/127.0f, 1e-12f), v8si = 1.0f/v8s;
  __shared__ float tile[64][65];
  int bkv = blockIdx.z, t0 = blockIdx.x << 6, d0 = blockIdx.y << 6;
  int b = bkv >> 3, kv = bkv & 7;
  const float* src = vlin + ((size_t)(b << 10))*1024 + (size_t)kv*128;
  int tx = threadIdx.x & 63, tq = threadIdx.x >> 6;
  #pragma unroll
  for (int i = 0; i < 16; i++){
    int tt = (i << 2) + tq;
    float x = src[(size_t)(t0 + tt)*1024 + d0 + tx];
    tile[tx][tt] = fq8(fqa(x, pv), v8s, v8si);
  }
  __syncthreads();
  _Float16* dst = vT + (size_t)bkv*131072;
  #pragma unroll
  for (int i = 0; i < 16; i++){
    int dd = (i << 2) + tq;
    dst[(size_t)(d0 + dd)*1024 + t0 + tx] = (_Float16)tile[dd][tx];
  }
}

__global__ __launch_bounds__(256) void k_rowstat_m2(const unsigned* __restrict__ rowmin, unsigned* stats, int n){
  float lm = -FLT_MAX;
  for (int i = threadIdx.x; i < n; i += 256) lm = fmaxf(lm, o2f(rowmin[i]));
  __shared__ float red[256];
  float m = bred_max(lm, red);
  if (threadIdx.x == 0) stats[35*16] = f2o(m);
}
__global__ __launch_bounds__(256) void k_denom_min(const float* __restrict__ denomS, unsigned* stats, int n){
  float lm = FLT_MAX;
  for (int i = threadIdx.x; i < n; i += 256) lm = fminf(lm, denomS[i]);
  __shared__ float red[256];
  float m = bred_min(lm, red);
  if (threadIdx.x == 0) stats[32*16] = f2o(m);
}

struct LogitQ { FQP f1, f2, fam, fvv, f3; float sc, c20; };
__device__ LogitQ derive_logit(const unsigned* st){
  LogitQ L;
  FQP ps = fqp(SCALING_F, SCALING_F); L.sc = fqa(SCALING_F, ps);
  FQP p20 = fqp(-20.0f, -20.0f);      L.c20 = fqa(-20.0f, p20);
  float gmn = dec_slot(st, 28), gmx = dec_slot(st, 29);
  float gU = dec_slot(st, 31), M2 = dec_slot(st, 35);
  L.f1 = fqp(gmn, gmx);
  float l1lo = fqa(gmn, L.f1), l1hi = fqa(gmx, L.f1);
  L.f2 = fqp(l1lo*L.sc, l1hi*L.sc);
  float amlo = fqa(fqa(gmn, L.f1)*L.sc, L.f2);
  float amhi = fqa(fqa(M2, L.f1)*L.sc, L.f2);
  L.fam = fqp(amlo, amhi);
  float vslo = fqa(amlo, L.fam) + L.c20, vshi = fqa(amhi, L.fam) + L.c20;
  L.fvv = fqp(vslo, vshi);
  float mn3 = fqa(vslo, L.fvv);
  float mx3 = fqa(fqa(gU, L.f1)*L.sc, L.f2);
  L.f3 = fqp(mn3, mx3);
  return L;
}
// unmasked chain raw -> a3
__device__ __forceinline__ float chainU(float raw, const LogitQ& L){
  return fqa(fqa(fqa(raw, L.f1)*L.sc, L.f2), L.f3);
}
__device__ __forceinline__ float row_vv3(const unsigned* rowmin, int row, const LogitQ& L){
  float tr = fqa(fqa(o2f(rowmin[row]), L.f1)*L.sc, L.f2);
  return fqa(fqa(fqa(tr, L.fam) + L.c20, L.fvv), L.f3);
}

// single pass: per-row softmax denominator (m analytic from rowmax)
__global__ __launch_bounds__(256) void k_softmax_denom(const float* __restrict__ logits,
                                                       const unsigned* __restrict__ rowmin,
                                                       const unsigned* __restrict__ rowmax,
                                                       float* __restrict__ denomS,
                                                       const unsigned* stats){
  LogitQ L = derive_logit(stats);
  int row = blockIdx.x, s = row & 1023, tid = threadIdx.x;
  float vv3 = row_vv3(rowmin, row, L);
  float m = chainU(o2f(rowmax[row]), L);
  const float* rp = logits + ((size_t)row << 10);
  float4 v = *(const float4*)(rp + (tid << 2));
  float xs[4] = {v.x, v.y, v.z, v.w};
  float ls = 0.0f;
  #pragma unroll
  for (int j = 0; j < 4; j++){
    int t = (tid << 2) + j;
    float a2 = fqa(fqa(xs[j], L.f1)*L.sc, L.f2);
    float a3 = (t <= s) ? fqa(a2, L.f3) : vv3;
    ls += __expf(a3 - m);
  }
  __shared__ float red[256];
  float dn = bred_sum(ls, red);
  if (tid == 0) denomS[row] = dn;
}

// PV with fused softmax-finalize: stages A by reading RAW logits, computes
// pq = fq16(exp(a3-m)/dn), writes pq to the attn output (in place over raw),
// feeds pq*1024 (f16) to MFMA. Each raw element touched exactly once.
__global__ __launch_bounds__(256) void k_hgemm_pv(float* __restrict__ pat, const _Float16* __restrict__ vT,
                                                  float* __restrict__ ctx,
                                                  const unsigned* __restrict__ rowmin,
                                                  const unsigned* __restrict__ rowmax,
                                                  const float* __restrict__ denomS,
                                                  unsigned* stats){
  __shared__ __align__(16) _Float16 As[4096], Bs[4096];
  __shared__ float red[256];
  f4_t acc[4][4];
  { f4_t zz = {0.f,0.f,0.f,0.f}; for (int i=0;i<4;i++) for (int j=0;j<4;j++) acc[i][j]=zz; }
  int tid = threadIdx.x;
  int lane = tid & 63, wave = tid >> 6;
  int wm = wave & 1, wn = wave >> 1, quad = lane >> 4, l15 = lane & 15;
  LogitQ L = derive_logit(stats);
  float maxp = 1.0f/dec_slot(stats, 32);
  FQP p4 = fqp(0.0f, maxp);
  int z = blockIdx.z, b = z >> 4, h = z & 15;
  int bm = blockIdx.y << 7;
  // per-thread staging rows: rA (iter 0) and rA+64 (iter 1)
  int rA = tid >> 2;
  int gA = (z << 10) + bm + rA, gB = gA + 64;
  float vvA = row_vv3(rowmin, gA, L), vvB = row_vv3(rowmin, gB, L);
  float mA = chainU(o2f(rowmax[gA]), L), mB = chainU(o2f(rowmax[gB]), L);
  float rdA = 1.0f/denomS[gA], rdB = 1.0f/denomS[gB];
  float* base = pat + ((size_t)z << 20) + (size_t)bm*1024;
  const _Float16* Bb = vT + (size_t)(b*8 + (h>>1))*131072;
  for (int k0 = 0; k0 < 1024; k0 += 32){
    __syncthreads();
    #pragma unroll
    for (int it = 0; it < 2; it++){
      int c = tid + (it << 8);
      int row = c >> 2, off = (c & 3) << 3;
      int srow = bm + row, t0 = k0 + off;
      float vv = it ? vvB : vvA, mm = it ? mB : mA, rd = it ? rdB : rdA;
      float* sp = base + (size_t)row*1024 + t0;
      float4 u = *(const float4*)sp, w = *(const float4*)(sp + 4);
      float xs[8] = {u.x, u.y, u.z, u.w, w.x, w.y, w.z, w.w};
      float pr[8]; h8_t o;
      #pragma unroll
      for (int j = 0; j < 8; j++){
        float a2 = fqa(fqa(xs[j], L.f1)*L.sc, L.f2);
        float a3 = (t0 + j <= srow) ? fqa(a2, L.f3) : vv;
        float pq = fqa(__expf(a3 - mm)*rd, p4);
        pr[j] = pq; o[j] = (_Float16)(pq*1024.0f);
      }
      *(float4*)sp       = make_float4(pr[0], pr[1], pr[2], pr[3]);
      *(float4*)(sp + 4) = make_float4(pr[4], pr[5], pr[6], pr[7]);
      *(h8_t*)(As + (c << 3)) = o;
    }
    stage_tile(Bb, 1024, k0, Bs);
    __syncthreads();
    h8_t af[4], bf[4];
    #pragma unroll
    for (int mt = 0; mt < 4; mt++)
      af[mt] = *(const h8_t*)(As + ((((wm<<6) + (mt<<4) + l15)) << 5) + (quad << 3));
    #pragma unroll
    for (int nt = 0; nt < 4; nt++)
      bf[nt] = *(const h8_t*)(Bs + ((((wn<<6) + (nt<<4) + l15)) << 5) + (quad << 3));
    #pragma unroll
    for (int mt = 0; mt < 4; mt++)
      #pragma unroll
      for (int nt = 0; nt < 4; nt++)
        acc[mt][nt] = __builtin_amdgcn_mfma_f32_16x16x32_f16(af[mt], bf[nt], acc[mt][nt], 0, 0, 0);
  }
  float* Cb = ctx + ((size_t)b << 10)*2048 + (size_t)h*128;
  float mn = FLT_MAX, mx = -FLT_MAX;
  #pragma unroll
  for (int mt = 0; mt < 4; mt++)
    #pragma unroll
    for (int nt = 0; nt < 4; nt++){
      int Cc = (wn<<6) + (nt<<4) + l15;
      #pragma unroll
      for (int i = 0; i < 4; i++){
        int R = bm + (wm<<6) + (mt<<4) + (quad<<2) + i;
        float v = acc[mt][nt][i] * (1.0f/1024.0f);
        Cb[(size_t)R*2048 + Cc] = v;
        mn = fminf(mn, v); mx = fmaxf(mx, v);
      }
    }
  float bmn = bred_min(mn, red), bmx = bred_max(mx, red);
  if (tid == 0){ atomicMin(&stats[36*16], f2o(bmn)); atomicMax(&stats[37*16], f2o(bmx)); }
}

extern "C" void kernel_launch(void* const* d_in, const int* in_sizes, int n_in,
                              void* d_out, int out_size, void* d_ws, size_t ws_size,
                              hipStream_t stream){
  (void)in_sizes; (void)n_in; (void)out_size; (void)ws_size;
  const float* hs   = (const float*)d_in[0];
  const float* cosp = (const float*)d_in[1];
  const float* sinp = (const float*)d_in[2];
  const float* Wq   = (const float*)d_in[4];
  const float* Wk   = (const float*)d_in[5];
  const float* Wv   = (const float*)d_in[6];
  const float* Wo   = (const float*)d_in[7];
  const float* qnw  = (const float*)d_in[8];
  const float* knw  = (const float*)d_in[9];

  float* outp = (float*)d_out;
  float* attn = outp + 4194304;      // raw logits, finalized in-place by PV

  const size_t MEG = 1u << 20;       // floats
  float* wsf = (float*)d_ws;
  _Float16* woq_h = (_Float16*)(wsf + 0);
  _Float16* wqq_h = (_Float16*)(wsf + 2*MEG);
  _Float16* wkq_h = (_Float16*)(wsf + 4*MEG);
  _Float16* wvq_h = (_Float16*)(wsf + 5*MEG);
  _Float16* hsq_h = (_Float16*)(wsf + 6*MEG);
  float* qlin = wsf + 8*MEG;  float* ctx = qlin;   // ctx reuses qlin
  float* klin = wsf + 12*MEG;
  float* vlin = wsf + 14*MEG;
  float* qbuf = wsf + 16*MEG;
  float* kbuf = wsf + 20*MEG;
  _Float16* q_h   = (_Float16*)(wsf + 22*MEG);
  _Float16* k_h   = (_Float16*)(wsf + 24*MEG);
  _Float16* vT_h  = (_Float16*)(wsf + 25*MEG);
  _Float16* ctx_h = (_Float16*)(wsf + 26*MEG);
  unsigned* rowmin = (unsigned*)(wsf + 28*MEG);
  unsigned* rowmax = (unsigned*)(wsf + 28*MEG + 32768);
  float* denomS = wsf + 28*MEG + 65536;
  unsigned* stats = (unsigned*)(wsf + 28*MEG + 98304);

  k_init<<<128, 256, 0, stream>>>(stats, rowmin, rowmax, 32768);

  k_quantw<<<4096, 256, 0, stream>>>(Wq, wqq_h);
  k_quantw<<<2048, 256, 0, stream>>>(Wk, wkq_h);
  k_quantw<<<2048, 256, 0, stream>>>(Wv, wvq_h);
  k_quantw<<<4096, 256, 0, stream>>>(Wo, woq_h);

  k_minmax<<<1024, 256, 0, stream>>>(hs, 4194304, stats, 0);
  k_fq_ew16<<<4096, 256, 0, stream>>>(hs, hsq_h, stats, 0);

  // projections (f16 MFMA), raw-output range stats in epilogue
  k_hgemm_f<<<dim3(16, 16), 256, 0, stream>>>(hsq_h, wqq_h, qlin, 2048, 2048, stats, 2);
  k_hgemm_kv<<<dim3(8, 16, 2), 256, 0, stream>>>(hsq_h, wkq_h, wvq_h, klin, vlin, 2048, stats);

  // fq16 + rmsnorm (fp32) + range reductions
  k_rms<<<1024, 256, 0, stream>>>(qlin, qbuf, qnw, stats, 2, 8, 16, 32768);
  k_rms<<<512, 256, 0, stream>>>(klin, kbuf, knw, stats, 4, 12, 8, 16384);

  // RoPE: range pass then write pass
  k_rope<<<1024, 256, 0, stream>>>(qbuf, cosp, sinp, stats, 8, 16, 24, 16, 32768, 0);
  k_rope<<<512, 256, 0, stream>>>(kbuf, cosp, sinp, stats, 12, 20, 26, 8, 16384, 0);
  k_rope<<<1024, 256, 0, stream>>>(qbuf, cosp, sinp, stats, 8, 16, 24, 16, 32768, 1);
  k_rope<<<512, 256, 0, stream>>>(kbuf, cosp, sinp, stats, 12, 20, 26, 8, 16384, 1);

  // operand conversion for QK and V transpose
  k_fq_ew16<<<4096, 256, 0, stream>>>(qbuf, q_h, stats, 24);
  k_fq8_ew16<<<2048, 256, 0, stream>>>(kbuf, k_h, stats, 26);
  k_vT<<<dim3(16, 2, 16), 256, 0, stream>>>(vlin, vT_h, stats);

  // QK^T raw logits + stats + per-row min/unmasked-max
  k_hgemm_qk<<<dim3(8, 8, 32), 256, 0, stream>>>(q_h, k_h, attn, stats, rowmin, rowmax);
  k_rowstat_m2<<<1, 256, 0, stream>>>(rowmin, stats, 32768);

  // one read pass: per-row denominators; then global denom-min
  k_softmax_denom<<<32768, 256, 0, stream>>>(attn, rowmin, rowmax, denomS, stats);
  k_denom_min<<<1, 256, 0, stream>>>(denomS, stats, 32768);

  // PV with fused softmax finalize + attn write; then fq16 -> f16; O-proj
  k_hgemm_pv<<<dim3(1, 8, 32), 256, 0, stream>>>(attn, vT_h, ctx, rowmin, rowmax, denomS, stats);
  k_fq_ew16<<<4096, 256, 0, stream>>>(ctx, ctx_h, stats, 36);
  k_hgemm_f<<<dim3(16, 16), 256, 0, stream>>>(ctx_h, woq_h, outp, 2048, 2048, stats, -1);
}